// Round 7
// baseline (991.035 us; speedup 1.0000x reference)
//
#include <hip/hip_runtime.h>
#include <hip/hip_bf16.h>
#include <cstddef>
#include <cstdint>

#define TPB 256
#define HID 128
#define GATD 512
#define HEADS 4

typedef __attribute__((ext_vector_type(8))) short bf16x8;
typedef __attribute__((ext_vector_type(4))) float f32x4;

__device__ __forceinline__ float lrelu02(float x) { return x > 0.0f ? x : 0.2f * x; }

__device__ __forceinline__ unsigned short f2bf_rn(float f) {
  uint32_t u = __float_as_uint(f);
  u += 0x7fff + ((u >> 16) & 1);
  return (unsigned short)(u >> 16);
}
__device__ __forceinline__ float bf2f(unsigned short h) {
  return __uint_as_float(((uint32_t)h) << 16);
}
__device__ __forceinline__ float bflo(uint32_t u) { return __uint_as_float(u << 16); }
__device__ __forceinline__ float bfhi(uint32_t u) { return __uint_as_float(u & 0xffff0000u); }

#define GLD16(gsrc, ldst)                                                          \
  __builtin_amdgcn_global_load_lds(                                                \
      (const __attribute__((address_space(1))) unsigned int*)(gsrc),               \
      (__attribute__((address_space(3))) unsigned int*)(ldst), 16, 0, 0)

// ---------------- utility ----------------
__global__ void k_zero(int* __restrict__ p, int n) {
  int i = blockIdx.x * blockDim.x + threadIdx.x;
  if (i < n) p[i] = 0;
}

// ---------------- CSR build ----------------
__global__ void k_hist(const int* __restrict__ dst, int* __restrict__ cnt, int E) {
  int i = blockIdx.x * blockDim.x + threadIdx.x;
  if (i < E) atomicAdd(&cnt[dst[i]], 1);
}

__global__ __launch_bounds__(256) void k_scan_blk(const int* __restrict__ cnt,
                                                  int* __restrict__ rowp,
                                                  int* __restrict__ bsum,
                                                  float* __restrict__ dinv, int n) {
  __shared__ int wsum[4];
  const int tid = threadIdx.x, lane = tid & 63, wid = tid >> 6;
  const int base = blockIdx.x * 1024 + tid * 4;
  int v[4];
#pragma unroll
  for (int q = 0; q < 4; ++q) {
    int idx = base + q;
    v[q] = (idx < n) ? cnt[idx] : 0;
    if (idx < n) dinv[idx] = rsqrtf((float)(v[q] + 1));  // +1 self loop
  }
  int s = v[0] + v[1] + v[2] + v[3];
  int sc = s;
#pragma unroll
  for (int off = 1; off < 64; off <<= 1) {
    int t = __shfl_up(sc, off);
    if (lane >= off) sc += t;
  }
  if (lane == 63) wsum[wid] = sc;
  __syncthreads();
  int woff = 0;
#pragma unroll
  for (int w = 0; w < 4; ++w)
    if (w < wid) woff += wsum[w];
  int run = woff + sc - s;
#pragma unroll
  for (int q = 0; q < 4; ++q) {
    int idx = base + q;
    if (idx < n) rowp[idx] = run;
    run += v[q];
  }
  if (tid == 255) bsum[blockIdx.x] = woff + sc;
}

__global__ __launch_bounds__(256) void k_scan_top(int* __restrict__ bsum, int nb) {
  __shared__ int sm[256];
  const int tid = threadIdx.x;
  int v = (tid < nb) ? bsum[tid] : 0;
  sm[tid] = v;
  __syncthreads();
  for (int off = 1; off < 256; off <<= 1) {
    int t = (tid >= off) ? sm[tid - off] : 0;
    __syncthreads();
    sm[tid] += t;
    __syncthreads();
  }
  int incl = sm[tid];
  if (tid < nb) bsum[tid] = incl - v;
  if (tid == nb - 1) bsum[nb] = incl;
}

__global__ void k_scan_add(int* __restrict__ rowp, const int* __restrict__ bsum,
                           int n, int nb) {
  int i = blockIdx.x * blockDim.x + threadIdx.x;
  if (i < n) rowp[i] += bsum[i >> 10];
  if (i == 0) rowp[n] = bsum[nb];
}

__global__ void k_fill(const int* __restrict__ src, const int* __restrict__ dst,
                       const int* __restrict__ rowp, int* __restrict__ cur,
                       int* __restrict__ colsrc, int E) {
  int i = blockIdx.x * blockDim.x + threadIdx.x;
  if (i < E) {
    int d = dst[i];
    int pos = rowp[d] + atomicAdd(&cur[d], 1);
    colsrc[pos] = src[i];
  }
}

// ---------------- one-time splits ----------------
__global__ void k_splitx(const float* __restrict__ x, unsigned short* __restrict__ xh,
                         unsigned short* __restrict__ xl, long n) {
  long i = (long)blockIdx.x * blockDim.x + threadIdx.x;
  if (i < n) {
    float v = x[i];
    unsigned short h = f2bf_rn(v);
    xh[i] = h;
    xl[i] = f2bf_rn(v - bf2f(h));
  }
}

__global__ void k_splitw_all(const float* __restrict__ Win, const float* __restrict__ Wg1,
                             const float* __restrict__ Wg2, const float* __restrict__ Wgat,
                             const float* __restrict__ Wao, const float* __restrict__ Wout,
                             unsigned short* __restrict__ WinTh, unsigned short* __restrict__ WinTl,
                             unsigned short* __restrict__ Wg1Th, unsigned short* __restrict__ Wg1Tl,
                             unsigned short* __restrict__ Wg2Th, unsigned short* __restrict__ Wg2Tl,
                             unsigned short* __restrict__ WgatTh, unsigned short* __restrict__ WgatTl,
                             unsigned short* __restrict__ WaoTh, unsigned short* __restrict__ WaoTl,
                             unsigned short* __restrict__ WoutTh, unsigned short* __restrict__ WoutTl) {
  int t = blockIdx.x * blockDim.x + threadIdx.x;
  const float* W;
  unsigned short *H, *L;
  int K, NC, r;
  if (t < 32768)       { W = Win;  H = WinTh;  L = WinTl;  K = 256; NC = 128; r = t; }
  else if (t < 49152)  { W = Wg1;  H = Wg1Th;  L = Wg1Tl;  K = 128; NC = 128; r = t - 32768; }
  else if (t < 65536)  { W = Wg2;  H = Wg2Th;  L = Wg2Tl;  K = 128; NC = 128; r = t - 49152; }
  else if (t < 131072) { W = Wgat; H = WgatTh; L = WgatTl; K = 128; NC = 512; r = t - 65536; }
  else if (t < 196608) { W = Wao;  H = WaoTh;  L = WaoTl;  K = 512; NC = 128; r = t - 131072; }
  else if (t < 204800) { W = Wout; H = WoutTh; L = WoutTl; K = 128; NC = 64;  r = t - 196608; }
  else return;
  int k = r / NC, n2 = r % NC;
  float v = W[r];
  unsigned short h = f2bf_rn(v);
  H[(size_t)n2 * K + k] = h;
  L[(size_t)n2 * K + k] = f2bf_rn(v - bf2f(h));
}

// ---------------- MFMA GEMM: counted-vmcnt pipelined, multi-buffer LDS ----------------
// BM=64. BN=64: 4-buf depth-2 (vmcnt 32/16/0). BN=128: 3-buf depth-1 (vmcnt 24/0).
// K = NS*32 compile-time. A as (Ah,Al)[M,K], W as (BhT,BlT)[NC,K].
// A*B ~= Ah*Bh + Ah*Bl + Al*Bh.  OUTM: 0=f32, 1=bf16, 2=hi/lo planes.
template <int BN, int NS, int WCF, bool RELU, bool BIAS, int OUTM>
__global__ __launch_bounds__(256) void k_gemm4(
    const unsigned short* __restrict__ Ah, const unsigned short* __restrict__ Al,
    const unsigned short* __restrict__ BhT, const unsigned short* __restrict__ BlT,
    const float* __restrict__ bias, void* __restrict__ Cv, void* __restrict__ Cv2,
    int M, int NC) {
  constexpr int K = NS * 32;
  constexpr int NBUF = (BN == 64) ? 4 : 3;
  constexpr int DEPTH = (BN == 64) ? 2 : 1;
  constexpr int RUNS = 8 + 8 * (BN / 64);
  __shared__ alignas(16) unsigned short As[NBUF][2][4][64][8];
  __shared__ alignas(16) unsigned short Bs[NBUF][2][4][BN][8];
  const int tid = threadIdx.x;
  const int lane = tid & 63;
  const int wid = tid >> 6;
  const int wr = wid >> 1, wc = wid & 1;
  const int m0 = blockIdx.x * 64;
  const int n0 = blockIdx.y * BN;
  const int fr = lane & 15, g = lane >> 4;
  const bool arow_ok = (m0 + lane) < M;

  f32x4 acc[2][WCF];
#pragma unroll
  for (int mr = 0; mr < 2; ++mr)
#pragma unroll
    for (int nc = 0; nc < WCF; ++nc) acc[mr][nc] = (f32x4){0.f, 0.f, 0.f, 0.f};

  auto stage = [&](int d, int kk) {
    for (int rr = wid; rr < RUNS; rr += 4) {
      const int p = rr & 1;
      const int kg = (rr >> 1) & 3;
      if (rr < 8) {
        const unsigned short* sp = (p ? Al : Ah) + (size_t)(m0 + lane) * K + kk + kg * 8;
        if (arow_ok) GLD16(sp, &As[d][p][kg][0][0]);
      } else {
        const int cb = (rr - 8) >> 3;
        const unsigned short* sp =
            (p ? BlT : BhT) + (size_t)(n0 + cb * 64 + lane) * K + kk + kg * 8;
        GLD16(sp, &Bs[d][p][kg][cb * 64][0]);
      }
    }
  };

  stage(0, 0);
  if (DEPTH == 2 && NS > 1) stage(1, 32);

#pragma unroll
  for (int s = 0; s < NS; ++s) {
    const int b = s % NBUF;
    if (s + DEPTH < NS) stage((s + DEPTH) % NBUF, (s + DEPTH) * 32);
    // counted waits: never drain prefetch (T4). constants per structure.
    if (BN == 64) {
      if (s + 2 < NS)      asm volatile("s_waitcnt vmcnt(32)" ::: "memory");
      else if (s + 1 < NS) asm volatile("s_waitcnt vmcnt(16)" ::: "memory");
      else                 asm volatile("s_waitcnt vmcnt(0)" ::: "memory");
    } else {
      if (s + 1 < NS)      asm volatile("s_waitcnt vmcnt(24)" ::: "memory");
      else                 asm volatile("s_waitcnt vmcnt(0)" ::: "memory");
    }
    __builtin_amdgcn_s_barrier();
    asm volatile("" ::: "memory");  // keep ds_reads below the barrier
    bf16x8 ah[2], al[2], bh[WCF], bl[WCF];
#pragma unroll
    for (int mr = 0; mr < 2; ++mr) {
      const int row = wr * 32 + mr * 16 + fr;
      ah[mr] = *(const bf16x8*)&As[b][0][g][row][0];
      al[mr] = *(const bf16x8*)&As[b][1][g][row][0];
    }
#pragma unroll
    for (int nc = 0; nc < WCF; ++nc) {
      const int col = wc * WCF * 16 + nc * 16 + fr;
      bh[nc] = *(const bf16x8*)&Bs[b][0][g][col][0];
      bl[nc] = *(const bf16x8*)&Bs[b][1][g][col][0];
    }
#pragma unroll
    for (int mr = 0; mr < 2; ++mr)
#pragma unroll
      for (int nc = 0; nc < WCF; ++nc) {
        acc[mr][nc] = __builtin_amdgcn_mfma_f32_16x16x32_bf16(ah[mr], bh[nc], acc[mr][nc], 0, 0, 0);
        acc[mr][nc] = __builtin_amdgcn_mfma_f32_16x16x32_bf16(ah[mr], bl[nc], acc[mr][nc], 0, 0, 0);
        acc[mr][nc] = __builtin_amdgcn_mfma_f32_16x16x32_bf16(al[mr], bh[nc], acc[mr][nc], 0, 0, 0);
      }
  }
  // ---- epilogue ----
#pragma unroll
  for (int mr = 0; mr < 2; ++mr) {
#pragma unroll
    for (int nc = 0; nc < WCF; ++nc) {
      const int col = n0 + wc * WCF * 16 + nc * 16 + fr;
      const float bv = BIAS ? bias[col] : 0.f;
#pragma unroll
      for (int r = 0; r < 4; ++r) {
        const int grow = m0 + wr * 32 + mr * 16 + g * 4 + r;
        if (grow < M) {
          float v = acc[mr][nc][r] + bv;
          if (RELU) v = fmaxf(v, 0.f);
          const size_t idx = (size_t)grow * NC + col;
          if (OUTM == 0) {
            ((float*)Cv)[idx] = v;
          } else if (OUTM == 1) {
            ((unsigned short*)Cv)[idx] = f2bf_rn(v);
          } else {
            unsigned short h = f2bf_rn(v);
            ((unsigned short*)Cv)[idx] = h;
            ((unsigned short*)Cv2)[idx] = f2bf_rn(v - bf2f(h));
          }
        }
      }
    }
  }
}

// ---------------- GCN aggregate + bias + LN + ReLU (+residual, +fused GAT logits) ----------------
template <bool L2>
__global__ __launch_bounds__(256) void k_gcn_agg(
    const float* __restrict__ xw, const float* __restrict__ dinv,
    const int* __restrict__ rowp, const int* __restrict__ colsrc,
    const float* __restrict__ bias, const float* __restrict__ gamma,
    const float* __restrict__ beta,
    const unsigned short* __restrict__ resh, const unsigned short* __restrict__ resl,
    unsigned short* __restrict__ oh, unsigned short* __restrict__ ol,
    const float* __restrict__ waT, float* __restrict__ a_s, float* __restrict__ a_d,
    int n) {
  __shared__ float w[8][HID];
  if (L2) {
    for (int t = threadIdx.x; t < 8 * HID; t += 256) ((float*)w)[t] = waT[t];
    __syncthreads();
  }
  const int lane = threadIdx.x & 63;
  const int i = blockIdx.x * 4 + (threadIdx.x >> 6);
  if (i >= n) return;
  const float di = dinv[i];
  const int c = lane * 2;
  float2 v = *(const float2*)(xw + (size_t)i * HID + c);
  float a0 = v.x * di * di, a1 = v.y * di * di;  // self loop
  const int e0 = rowp[i], e1 = rowp[i + 1];
  for (int j = e0; j < e1; ++j) {
    int s = colsrc[j];
    float wgt = dinv[s] * di;
    float2 u = *(const float2*)(xw + (size_t)s * HID + c);
    a0 = fmaf(u.x, wgt, a0);
    a1 = fmaf(u.y, wgt, a1);
  }
  a0 += bias[c];
  a1 += bias[c + 1];
  float s1 = a0 + a1, s2 = a0 * a0 + a1 * a1;
#pragma unroll
  for (int m = 32; m >= 1; m >>= 1) {
    s1 += __shfl_xor(s1, m);
    s2 += __shfl_xor(s2, m);
  }
  float mu = s1 * (1.0f / HID);
  float var = s2 * (1.0f / HID) - mu * mu;
  float rstd = rsqrtf(var + 1e-5f);
  float y0 = fmaxf((a0 - mu) * rstd * gamma[c] + beta[c], 0.0f);
  float y1 = fmaxf((a1 - mu) * rstd * gamma[c + 1] + beta[c + 1], 0.0f);
  if (L2) {
    uint32_t rh = *(const uint32_t*)(resh + (size_t)i * HID + c);
    uint32_t rl = *(const uint32_t*)(resl + (size_t)i * HID + c);
    y0 += bflo(rh) + bflo(rl);
    y1 += bfhi(rh) + bfhi(rl);
  }
  unsigned short ph0 = f2bf_rn(y0), ph1 = f2bf_rn(y1);
  uint32_t hw = (uint32_t)ph0 | ((uint32_t)ph1 << 16);
  uint32_t lw = (uint32_t)f2bf_rn(y0 - bf2f(ph0)) |
                ((uint32_t)f2bf_rn(y1 - bf2f(ph1)) << 16);
  *(uint32_t*)(oh + (size_t)i * HID + c) = hw;
  *(uint32_t*)(ol + (size_t)i * HID + c) = lw;
  if (L2) {
    float p[8];
#pragma unroll
    for (int h = 0; h < 8; ++h) p[h] = y0 * w[h][c] + y1 * w[h][c + 1];
#pragma unroll
    for (int m = 32; m >= 1; m >>= 1) {
#pragma unroll
      for (int h = 0; h < 8; ++h) p[h] += __shfl_xor(p[h], m);
    }
    if (lane == 0) {
      a_s[i * 4 + 0] = p[0]; a_s[i * 4 + 1] = p[1];
      a_s[i * 4 + 2] = p[2]; a_s[i * 4 + 3] = p[3];
      a_d[i * 4 + 0] = p[4]; a_d[i * 4 + 1] = p[5];
      a_d[i * 4 + 2] = p[6]; a_d[i * 4 + 3] = p[7];
    }
  }
}

// ---------------- fold Wgat into attention vectors ----------------
__global__ __launch_bounds__(256) void k_wprep(const float* __restrict__ Wgat,
                                               const float* __restrict__ att_src,
                                               const float* __restrict__ att_dst,
                                               float* __restrict__ waT) {
  int t = blockIdx.x * blockDim.x + threadIdx.x;  // 0..1023
  if (t >= 1024) return;
  int p = t >> 7, k = t & 127;
  int h = p & 3;
  const float* av = (p < 4 ? att_src : att_dst) + h * HID;
  const float* wrow = Wgat + (size_t)k * GATD + h * HID;
  float s = 0.f;
#pragma unroll 4
  for (int c = 0; c < HID; ++c) s = fmaf(wrow[c], av[c], s);
  waT[t] = s;
}

// ---------------- GAT softmax-aggregate: alpha precompute + gather loop ----------------
__global__ __launch_bounds__(256) void k_gat_agg(const unsigned short* __restrict__ xwgb,
                                                 const float* __restrict__ a_s,
                                                 const float* __restrict__ a_d,
                                                 const int* __restrict__ rowp,
                                                 const int* __restrict__ colsrc,
                                                 const float* __restrict__ bias,
                                                 float* __restrict__ alf,
                                                 unsigned short* __restrict__ gath,
                                                 unsigned short* __restrict__ gatl,
                                                 int n) {
  const int lane = threadIdx.x & 63;
  const int i = blockIdx.x * 4 + (threadIdx.x >> 6);
  if (i >= n) return;
  const float4 adv = *(const float4*)(a_d + i * 4);
  const float4 asv = *(const float4*)(a_s + i * 4);
  float es0 = lrelu02(asv.x + adv.x);
  float es1 = lrelu02(asv.y + adv.y);
  float es2 = lrelu02(asv.z + adv.z);
  float es3 = lrelu02(asv.w + adv.w);
  const int e0 = rowp[i], e1 = rowp[i + 1];
  // pass 1: max
  float m0 = es0, m1 = es1, m2 = es2, m3 = es3;
  for (int j = e0 + lane; j < e1; j += 64) {
    int s = colsrc[j];
    const float4 av = *(const float4*)(a_s + s * 4);
    m0 = fmaxf(m0, lrelu02(av.x + adv.x));
    m1 = fmaxf(m1, lrelu02(av.y + adv.y));
    m2 = fmaxf(m2, lrelu02(av.z + adv.z));
    m3 = fmaxf(m3, lrelu02(av.w + adv.w));
  }
#pragma unroll
  for (int m = 32; m >= 1; m >>= 1) {
    m0 = fmaxf(m0, __shfl_xor(m0, m));
    m1 = fmaxf(m1, __shfl_xor(m1, m));
    m2 = fmaxf(m2, __shfl_xor(m2, m));
    m3 = fmaxf(m3, __shfl_xor(m3, m));
  }
  // pass 2: denom
  float d0 = 0.f, d1 = 0.f, d2 = 0.f, d3 = 0.f;
  for (int j = e0 + lane; j < e1; j += 64) {
    int s = colsrc[j];
    const float4 av = *(const float4*)(a_s + s * 4);
    d0 += __expf(lrelu02(av.x + adv.x) - m0);
    d1 += __expf(lrelu02(av.y + adv.y) - m1);
    d2 += __expf(lrelu02(av.z + adv.z) - m2);
    d3 += __expf(lrelu02(av.w + adv.w) - m3);
  }
#pragma unroll
  for (int m = 32; m >= 1; m >>= 1) {
    d0 += __shfl_xor(d0, m);
    d1 += __shfl_xor(d1, m);
    d2 += __shfl_xor(d2, m);
    d3 += __shfl_xor(d3, m);
  }
  d0 += __expf(es0 - m0);
  d1 += __expf(es1 - m1);
  d2 += __expf(es2 - m2);
  d3 += __expf(es3 - m3);
  const float inv0 = 1.0f / d0, inv1 = 1.0f / d1, inv2 = 1.0f / d2, inv3 = 1.0f / d3;
  // pass 2b: materialize per-edge alphas (lane-parallel, usually 1 iter)
  for (int j = e0 + lane; j < e1; j += 64) {
    int s = colsrc[j];
    const float4 av = *(const float4*)(a_s + s * 4);
    float4 al4 = make_float4(__expf(lrelu02(av.x + adv.x) - m0) * inv0,
                             __expf(lrelu02(av.y + adv.y) - m1) * inv1,
                             __expf(lrelu02(av.z + adv.z) - m2) * inv2,
                             __expf(lrelu02(av.w + adv.w) - m3) * inv3);
    *(float4*)(alf + (size_t)j * 4) = al4;
  }
  const int col = lane * 8;
  const int h = lane >> 4;
  const float mh = (h < 2) ? (h == 0 ? m0 : m1) : (h == 2 ? m2 : m3);
  const float invh = (h < 2) ? (h == 0 ? inv0 : inv1) : (h == 2 ? inv2 : inv3);
  const float esh = (h < 2) ? (h == 0 ? es0 : es1) : (h == 2 ? es2 : es3);
  const float aself = __expf(esh - mh) * invh;
  // lanes of this wave just wrote alf for this node's edges; wave-coherent (L1) reads follow.
  uint4 u = *(const uint4*)(xwgb + (size_t)i * GATD + col);
  float4 acc0 = make_float4(bflo(u.x) * aself, bfhi(u.x) * aself,
                            bflo(u.y) * aself, bfhi(u.y) * aself);
  float4 acc1 = make_float4(bflo(u.z) * aself, bfhi(u.z) * aself,
                            bflo(u.w) * aself, bfhi(u.w) * aself);
  // pass 3: gather loop, no transcendental in the body
  for (int j = e0; j < e1; ++j) {
    int s = colsrc[j];
    float al = alf[(size_t)j * 4 + h];
    uint4 w = *(const uint4*)(xwgb + (size_t)s * GATD + col);
    acc0.x = fmaf(bflo(w.x), al, acc0.x); acc0.y = fmaf(bfhi(w.x), al, acc0.y);
    acc0.z = fmaf(bflo(w.y), al, acc0.z); acc0.w = fmaf(bfhi(w.y), al, acc0.w);
    acc1.x = fmaf(bflo(w.z), al, acc1.x); acc1.y = fmaf(bfhi(w.z), al, acc1.y);
    acc1.z = fmaf(bflo(w.w), al, acc1.z); acc1.w = fmaf(bfhi(w.w), al, acc1.w);
  }
  const float4* bp = (const float4*)(bias + col);
  float4 b0 = bp[0], b1 = bp[1];
  float vv[8] = {acc0.x + b0.x, acc0.y + b0.y, acc0.z + b0.z, acc0.w + b0.w,
                 acc1.x + b1.x, acc1.y + b1.y, acc1.z + b1.z, acc1.w + b1.w};
  uint32_t hv[4], lv[4];
#pragma unroll
  for (int q = 0; q < 4; ++q) {
    unsigned short ha = f2bf_rn(vv[2 * q]), hb = f2bf_rn(vv[2 * q + 1]);
    unsigned short la = f2bf_rn(vv[2 * q] - bf2f(ha));
    unsigned short lb = f2bf_rn(vv[2 * q + 1] - bf2f(hb));
    hv[q] = (uint32_t)ha | ((uint32_t)hb << 16);
    lv[q] = (uint32_t)la | ((uint32_t)lb << 16);
  }
  *(uint4*)(gath + (size_t)i * GATD + col) = make_uint4(hv[0], hv[1], hv[2], hv[3]);
  *(uint4*)(gatl + (size_t)i * GATD + col) = make_uint4(lv[0], lv[1], lv[2], lv[3]);
}

extern "C" void kernel_launch(void* const* d_in, const int* in_sizes, int n_in,
                              void* d_out, int out_size, void* d_ws, size_t ws_size,
                              hipStream_t stream) {
  const float* x = (const float*)d_in[0];
  const int* ei = (const int*)d_in[1];
  const float* Win = (const float*)d_in[2];
  const float* bin = (const float*)d_in[3];
  const float* Wg1 = (const float*)d_in[4];
  const float* bg1 = (const float*)d_in[5];
  const float* g1g = (const float*)d_in[6];
  const float* g1b = (const float*)d_in[7];
  const float* Wg2 = (const float*)d_in[8];
  const float* bg2 = (const float*)d_in[9];
  const float* g2g = (const float*)d_in[10];
  const float* g2b = (const float*)d_in[11];
  const float* Wgat = (const float*)d_in[12];
  const float* att_s = (const float*)d_in[13];
  const float* att_d = (const float*)d_in[14];
  const float* bgat = (const float*)d_in[15];
  const float* Wao = (const float*)d_in[16];
  const float* bao = (const float*)d_in[17];
  const float* Wout = (const float*)d_in[18];
  const float* bout = (const float*)d_in[19];

  const int N = in_sizes[0] / 256;
  const int E = in_sizes[1] / 2;
  const int* src = ei;
  const int* dst = ei + E;

  // ---- workspace layout (bytes), ~211 MB ----
  char* base = (char*)d_ws;
  size_t off = 0;
  unsigned short* xh = (unsigned short*)(base + off);  off += (size_t)N * 256 * 2;
  unsigned short* xl = (unsigned short*)(base + off);  off += (size_t)N * 256 * 2;
  unsigned short* h0h = (unsigned short*)(base + off); off += (size_t)N * HID * 2;
  unsigned short* h0l = (unsigned short*)(base + off); off += (size_t)N * HID * 2;
  unsigned short* x1h = (unsigned short*)(base + off); off += (size_t)N * HID * 2;
  unsigned short* x1l = (unsigned short*)(base + off); off += (size_t)N * HID * 2;
  unsigned short* gath = xh;   // dead by GAT agg
  unsigned short* gatl = h0h;  // dead by GAT agg
  float* xw = (float*)(base + off);                    off += (size_t)N * HID * 4;
  float* alf = xw;             // xw dead after 2nd gcn_agg; E*4 floats <= N*128
  unsigned short* x2h = (unsigned short*)(base + off); off += (size_t)N * HID * 2;
  unsigned short* x2l = (unsigned short*)(base + off); off += (size_t)N * HID * 2;
  unsigned short* atth = x2h;  // reuse after Wgat GEMM
  unsigned short* attl = x2l;
  unsigned short* xwgb = (unsigned short*)(base + off); off += (size_t)N * GATD * 2;
  float* dinv = (float*)(base + off);                  off += (size_t)N * 4;
  float* a_s = (float*)(base + off);                   off += (size_t)N * 16;
  float* a_d = (float*)(base + off);                   off += (size_t)N * 16;
  float* waT = (float*)(base + off);                   off += 4096;
  unsigned short *WinTh, *WinTl, *Wg1Th, *Wg1Tl, *Wg2Th, *Wg2Tl;
  unsigned short *WgatTh, *WgatTl, *WaoTh, *WaoTl, *WoutTh, *WoutTl;
  WinTh = (unsigned short*)(base + off);  off += 256 * 128 * 2;
  WinTl = (unsigned short*)(base + off);  off += 256 * 128 * 2;
  Wg1Th = (unsigned short*)(base + off);  off += 128 * 128 * 2;
  Wg1Tl = (unsigned short*)(base + off);  off += 128 * 128 * 2;
  Wg2Th = (unsigned short*)(base + off);  off += 128 * 128 * 2;
  Wg2Tl = (unsigned short*)(base + off);  off += 128 * 128 * 2;
  WgatTh = (unsigned short*)(base + off); off += 128 * 512 * 2;
  WgatTl = (unsigned short*)(base + off); off += 128 * 512 * 2;
  WaoTh = (unsigned short*)(base + off);  off += 512 * 128 * 2;
  WaoTl = (unsigned short*)(base + off);  off += 512 * 128 * 2;
  WoutTh = (unsigned short*)(base + off); off += 128 * 64 * 2;
  WoutTl = (unsigned short*)(base + off); off += 128 * 64 * 2;
  int* rowp = (int*)(base + off);   off += (size_t)(N + 1) * 4;
  int* colsrc = (int*)(base + off); off += (size_t)E * 4;
  const int nb2 = (N + 1023) / 1024;
  int* bsum = (int*)(base + off);   off += (size_t)(nb2 + 2) * 4;
  int* cnt = (int*)xwgb;  // alias: dead before xwgb is written
  int* cur = cnt + N;

  const int eb = (E + TPB - 1) / TPB;
  const int zb = (2 * N + TPB - 1) / TPB;
  const int ab = (N + 3) / 4;
  const int gm = (N + 63) / 64;

  // CSR + prep
  k_zero<<<zb, TPB, 0, stream>>>(cnt, 2 * N);
  k_hist<<<eb, TPB, 0, stream>>>(dst, cnt, E);
  k_scan_blk<<<nb2, 256, 0, stream>>>(cnt, rowp, bsum, dinv, N);
  k_scan_top<<<1, 256, 0, stream>>>(bsum, nb2);
  k_scan_add<<<(N + 255) / 256, 256, 0, stream>>>(rowp, bsum, N, nb2);
  k_fill<<<eb, TPB, 0, stream>>>(src, dst, rowp, cur, colsrc, E);
  k_wprep<<<4, 256, 0, stream>>>(Wgat, att_s, att_d, waT);
  k_splitx<<<(int)(((long)N * 256 + 255) / 256), 256, 0, stream>>>(x, xh, xl, (long)N * 256);
  k_splitw_all<<<(204800 + 255) / 256, 256, 0, stream>>>(
      Win, Wg1, Wg2, Wgat, Wao, Wout, WinTh, WinTl, Wg1Th, Wg1Tl, Wg2Th, Wg2Tl,
      WgatTh, WgatTl, WaoTh, WaoTl, WoutTh, WoutTl);

  // h0 = relu(x @ Win + bin) -> planes      [K=256 -> NS=8]
  k_gemm4<64, 8, 2, true, true, 2><<<dim3(gm, 2), 256, 0, stream>>>(
      xh, xl, WinTh, WinTl, bin, h0h, h0l, N, 128);
  // GCN layer 1                              [K=128 -> NS=4]
  k_gemm4<64, 4, 2, false, false, 0><<<dim3(gm, 2), 256, 0, stream>>>(
      h0h, h0l, Wg1Th, Wg1Tl, nullptr, xw, nullptr, N, 128);
  k_gcn_agg<false><<<ab, 256, 0, stream>>>(xw, dinv, rowp, colsrc, bg1, g1g, g1b,
                                           nullptr, nullptr, x1h, x1l,
                                           nullptr, nullptr, nullptr, N);
  // GCN layer 2 (+residual, +fused GAT logits)
  k_gemm4<64, 4, 2, false, false, 0><<<dim3(gm, 2), 256, 0, stream>>>(
      x1h, x1l, Wg2Th, Wg2Tl, nullptr, xw, nullptr, N, 128);
  k_gcn_agg<true><<<ab, 256, 0, stream>>>(xw, dinv, rowp, colsrc, bg2, g2g, g2b,
                                          x1h, x1l, x2h, x2l, waT, a_s, a_d, N);
  // GAT: xwgb = bf16(x2 @ Wgat)              [BN=128, depth-1/3-buf]
  k_gemm4<128, 4, 4, false, false, 1><<<dim3(gm, 4), 256, 0, stream>>>(
      x2h, x2l, WgatTh, WgatTl, nullptr, xwgb, nullptr, N, 512);
  // softmax-aggregate -> gat planes (alf aliases dead xw)
  k_gat_agg<<<ab, 256, 0, stream>>>(xwgb, a_s, a_d, rowp, colsrc, bgat, alf, gath, gatl, N);
  // att = relu(gat @ Wao + bao) -> planes    [K=512 -> NS=16]
  k_gemm4<64, 16, 2, true, true, 2><<<dim3(gm, 2), 256, 0, stream>>>(
      gath, gatl, WaoTh, WaoTl, bao, atth, attl, N, 128);
  // out = att @ Wout + bout (fp32)           [NC=64]
  k_gemm4<64, 4, 2, false, true, 0><<<dim3(gm, 1), 256, 0, stream>>>(
      atth, attl, WoutTh, WoutTl, bout, d_out, nullptr, N, 64);
}

// Round 8
// 670.028 us; speedup vs baseline: 1.4791x; 1.4791x over previous
//
#include <hip/hip_runtime.h>
#include <hip/hip_bf16.h>
#include <cstddef>
#include <cstdint>

#define TPB 256
#define HID 128
#define GATD 512
#define HEADS 4

typedef __attribute__((ext_vector_type(8))) short bf16x8;
typedef __attribute__((ext_vector_type(4))) float f32x4;

__device__ __forceinline__ float lrelu02(float x) { return x > 0.0f ? x : 0.2f * x; }

__device__ __forceinline__ unsigned short f2bf_rn(float f) {
  uint32_t u = __float_as_uint(f);
  u += 0x7fff + ((u >> 16) & 1);
  return (unsigned short)(u >> 16);
}
__device__ __forceinline__ float bf2f(unsigned short h) {
  return __uint_as_float(((uint32_t)h) << 16);
}
__device__ __forceinline__ float bflo(uint32_t u) { return __uint_as_float(u << 16); }
__device__ __forceinline__ float bfhi(uint32_t u) { return __uint_as_float(u & 0xffff0000u); }

// ---------------- utility ----------------
__global__ void k_zero(int* __restrict__ p, int n) {
  int i = blockIdx.x * blockDim.x + threadIdx.x;
  if (i < n) p[i] = 0;
}

// ---------------- CSR build ----------------
__global__ void k_hist(const int* __restrict__ dst, int* __restrict__ cnt, int E) {
  int i = blockIdx.x * blockDim.x + threadIdx.x;
  if (i < E) atomicAdd(&cnt[dst[i]], 1);
}

__global__ __launch_bounds__(256) void k_scan_blk(const int* __restrict__ cnt,
                                                  int* __restrict__ rowp,
                                                  int* __restrict__ bsum,
                                                  float* __restrict__ dinv, int n) {
  __shared__ int wsum[4];
  const int tid = threadIdx.x, lane = tid & 63, wid = tid >> 6;
  const int base = blockIdx.x * 1024 + tid * 4;
  int v[4];
#pragma unroll
  for (int q = 0; q < 4; ++q) {
    int idx = base + q;
    v[q] = (idx < n) ? cnt[idx] : 0;
    if (idx < n) dinv[idx] = rsqrtf((float)(v[q] + 1));  // +1 self loop
  }
  int s = v[0] + v[1] + v[2] + v[3];
  int sc = s;
#pragma unroll
  for (int off = 1; off < 64; off <<= 1) {
    int t = __shfl_up(sc, off);
    if (lane >= off) sc += t;
  }
  if (lane == 63) wsum[wid] = sc;
  __syncthreads();
  int woff = 0;
#pragma unroll
  for (int w = 0; w < 4; ++w)
    if (w < wid) woff += wsum[w];
  int run = woff + sc - s;
#pragma unroll
  for (int q = 0; q < 4; ++q) {
    int idx = base + q;
    if (idx < n) rowp[idx] = run;
    run += v[q];
  }
  if (tid == 255) bsum[blockIdx.x] = woff + sc;
}

__global__ __launch_bounds__(256) void k_scan_top(int* __restrict__ bsum, int nb) {
  __shared__ int sm[256];
  const int tid = threadIdx.x;
  int v = (tid < nb) ? bsum[tid] : 0;
  sm[tid] = v;
  __syncthreads();
  for (int off = 1; off < 256; off <<= 1) {
    int t = (tid >= off) ? sm[tid - off] : 0;
    __syncthreads();
    sm[tid] += t;
    __syncthreads();
  }
  int incl = sm[tid];
  if (tid < nb) bsum[tid] = incl - v;
  if (tid == nb - 1) bsum[nb] = incl;
}

__global__ void k_scan_add(int* __restrict__ rowp, const int* __restrict__ bsum,
                           int n, int nb) {
  int i = blockIdx.x * blockDim.x + threadIdx.x;
  if (i < n) rowp[i] += bsum[i >> 10];
  if (i == 0) rowp[n] = bsum[nb];
}

__global__ void k_fill(const int* __restrict__ src, const int* __restrict__ dst,
                       const int* __restrict__ rowp, int* __restrict__ cur,
                       int* __restrict__ colsrc, int E) {
  int i = blockIdx.x * blockDim.x + threadIdx.x;
  if (i < E) {
    int d = dst[i];
    int pos = rowp[d] + atomicAdd(&cur[d], 1);
    colsrc[pos] = src[i];
  }
}

// ---------------- one-time splits ----------------
__global__ void k_splitx(const float* __restrict__ x, unsigned short* __restrict__ xh,
                         unsigned short* __restrict__ xl, long n) {
  long i = (long)blockIdx.x * blockDim.x + threadIdx.x;
  if (i < n) {
    float v = x[i];
    unsigned short h = f2bf_rn(v);
    xh[i] = h;
    xl[i] = f2bf_rn(v - bf2f(h));
  }
}

__global__ void k_splitw_all(const float* __restrict__ Win, const float* __restrict__ Wg1,
                             const float* __restrict__ Wg2, const float* __restrict__ Wgat,
                             const float* __restrict__ Wao, const float* __restrict__ Wout,
                             unsigned short* __restrict__ WinTh, unsigned short* __restrict__ WinTl,
                             unsigned short* __restrict__ Wg1Th, unsigned short* __restrict__ Wg1Tl,
                             unsigned short* __restrict__ Wg2Th, unsigned short* __restrict__ Wg2Tl,
                             unsigned short* __restrict__ WgatTh, unsigned short* __restrict__ WgatTl,
                             unsigned short* __restrict__ WaoTh, unsigned short* __restrict__ WaoTl,
                             unsigned short* __restrict__ WoutTh, unsigned short* __restrict__ WoutTl) {
  int t = blockIdx.x * blockDim.x + threadIdx.x;
  const float* W;
  unsigned short *H, *L;
  int K, NC, r;
  if (t < 32768)       { W = Win;  H = WinTh;  L = WinTl;  K = 256; NC = 128; r = t; }
  else if (t < 49152)  { W = Wg1;  H = Wg1Th;  L = Wg1Tl;  K = 128; NC = 128; r = t - 32768; }
  else if (t < 65536)  { W = Wg2;  H = Wg2Th;  L = Wg2Tl;  K = 128; NC = 128; r = t - 49152; }
  else if (t < 131072) { W = Wgat; H = WgatTh; L = WgatTl; K = 128; NC = 512; r = t - 65536; }
  else if (t < 196608) { W = Wao;  H = WaoTh;  L = WaoTl;  K = 512; NC = 128; r = t - 131072; }
  else if (t < 204800) { W = Wout; H = WoutTh; L = WoutTl; K = 128; NC = 64;  r = t - 196608; }
  else return;
  int k = r / NC, n2 = r % NC;
  float v = W[r];
  unsigned short h = f2bf_rn(v);
  H[(size_t)n2 * K + k] = h;
  L[(size_t)n2 * K + k] = f2bf_rn(v - bf2f(h));
}

// ---------------- weight-stationary MFMA GEMM ----------------
// C = act(A @ W + bias); A as (Ah,Al)[M,KTOT], W as (BhT,BlT)[NC,KTOT] (transposed planes).
// Block: 64 rows x NCB cols. Weights (both planes) for a KC-chunk live in LDS (32 KB);
// A fragments stream global->register (lane layout == MFMA A-frag layout; no LDS for A,
// no per-k-step barrier -- 2 barriers per chunk). A*B ~= Ah*Bh + Ah*Bl + Al*Bh.
// OUTM: 0=f32, 1=bf16, 2=hi/lo planes.
template <int KTOT, int KC, int NCB, bool RELU, bool BIAS, int OUTM>
__global__ __launch_bounds__(256) void k_gemm5(
    const unsigned short* __restrict__ Ah, const unsigned short* __restrict__ Al,
    const unsigned short* __restrict__ BhT, const unsigned short* __restrict__ BlT,
    const float* __restrict__ bias, void* __restrict__ Cv, void* __restrict__ Cv2,
    int M, int NC) {
  constexpr int NSUB = KC / 32;
  constexpr int NCHUNK = KTOT / KC;
  constexpr int NCF = NCB / 16;
  constexpr int UNITS = NSUB * 2 * 4 * NCB;  // 16B ds_write units per chunk
  __shared__ alignas(16) unsigned short Bs[NSUB][2][4][NCB][8];
  const int tid = threadIdx.x, lane = tid & 63, wid = tid >> 6;
  const int m0 = blockIdx.x * 64;
  const int n0 = blockIdx.y * NCB;
  const int fr = lane & 15, g = lane >> 4;
  const int arow = m0 + wid * 16 + fr;
  const bool aok = arow < M;
  const size_t abase = (size_t)arow * KTOT;

  f32x4 acc[NCF];
#pragma unroll
  for (int cf = 0; cf < NCF; ++cf) acc[cf] = (f32x4){0.f, 0.f, 0.f, 0.f};

  for (int c = 0; c < NCHUNK; ++c) {
    const int c0 = c * KC;
    if (c > 0) __syncthreads();  // previous chunk's reads done
#pragma unroll
    for (int it = 0; it < UNITS / 256; ++it) {
      const int u = tid + it * 256;
      const int n = u % NCB;
      int rest = u / NCB;
      const int kg = rest & 3;
      rest >>= 2;
      const int p = rest & 1;
      const int sub = rest >> 1;
      const unsigned short* sp =
          (p ? BlT : BhT) + (size_t)(n0 + n) * KTOT + c0 + sub * 32 + kg * 8;
      *(uint4*)&Bs[sub][p][kg][n][0] = *(const uint4*)sp;
    }
    __syncthreads();
#pragma unroll
    for (int sub = 0; sub < NSUB; ++sub) {
      const int kb = c0 + sub * 32 + g * 8;
      bf16x8 a_h = {}, a_l = {};
      if (aok) {
        a_h = *(const bf16x8*)(Ah + abase + kb);
        a_l = *(const bf16x8*)(Al + abase + kb);
      }
#pragma unroll
      for (int cf = 0; cf < NCF; ++cf) {
        bf16x8 b_h = *(const bf16x8*)&Bs[sub][0][g][cf * 16 + fr][0];
        bf16x8 b_l = *(const bf16x8*)&Bs[sub][1][g][cf * 16 + fr][0];
        acc[cf] = __builtin_amdgcn_mfma_f32_16x16x32_bf16(a_h, b_h, acc[cf], 0, 0, 0);
        acc[cf] = __builtin_amdgcn_mfma_f32_16x16x32_bf16(a_h, b_l, acc[cf], 0, 0, 0);
        acc[cf] = __builtin_amdgcn_mfma_f32_16x16x32_bf16(a_l, b_h, acc[cf], 0, 0, 0);
      }
    }
  }
  // ---- epilogue: D layout col=lane&15, row=(lane>>4)*4+r ----
#pragma unroll
  for (int cf = 0; cf < NCF; ++cf) {
    const int col = n0 + cf * 16 + fr;
    const float bv = BIAS ? bias[col] : 0.f;
#pragma unroll
    for (int r = 0; r < 4; ++r) {
      const int grow = m0 + wid * 16 + g * 4 + r;
      if (grow < M) {
        float v = acc[cf][r] + bv;
        if (RELU) v = fmaxf(v, 0.f);
        const size_t idx = (size_t)grow * NC + col;
        if (OUTM == 0) {
          ((float*)Cv)[idx] = v;
        } else if (OUTM == 1) {
          ((unsigned short*)Cv)[idx] = f2bf_rn(v);
        } else {
          unsigned short h = f2bf_rn(v);
          ((unsigned short*)Cv)[idx] = h;
          ((unsigned short*)Cv2)[idx] = f2bf_rn(v - bf2f(h));
        }
      }
    }
  }
}

// ---------------- GCN aggregate + bias + LN + ReLU (+residual, +fused GAT logits) ----------------
template <bool L2>
__global__ __launch_bounds__(256) void k_gcn_agg(
    const float* __restrict__ xw, const float* __restrict__ dinv,
    const int* __restrict__ rowp, const int* __restrict__ colsrc,
    const float* __restrict__ bias, const float* __restrict__ gamma,
    const float* __restrict__ beta,
    const unsigned short* __restrict__ resh, const unsigned short* __restrict__ resl,
    unsigned short* __restrict__ oh, unsigned short* __restrict__ ol,
    const float* __restrict__ waT, float* __restrict__ a_s, float* __restrict__ a_d,
    int n) {
  __shared__ float w[8][HID];
  if (L2) {
    for (int t = threadIdx.x; t < 8 * HID; t += 256) ((float*)w)[t] = waT[t];
    __syncthreads();
  }
  const int lane = threadIdx.x & 63;
  const int i = blockIdx.x * 4 + (threadIdx.x >> 6);
  if (i >= n) return;
  const float di = dinv[i];
  const int c = lane * 2;
  float2 v = *(const float2*)(xw + (size_t)i * HID + c);
  float a0 = v.x * di * di, a1 = v.y * di * di;  // self loop
  const int e0 = rowp[i], e1 = rowp[i + 1];
  for (int j = e0; j < e1; ++j) {
    int s = colsrc[j];
    float wgt = dinv[s] * di;
    float2 u = *(const float2*)(xw + (size_t)s * HID + c);
    a0 = fmaf(u.x, wgt, a0);
    a1 = fmaf(u.y, wgt, a1);
  }
  a0 += bias[c];
  a1 += bias[c + 1];
  float s1 = a0 + a1, s2 = a0 * a0 + a1 * a1;
#pragma unroll
  for (int m = 32; m >= 1; m >>= 1) {
    s1 += __shfl_xor(s1, m);
    s2 += __shfl_xor(s2, m);
  }
  float mu = s1 * (1.0f / HID);
  float var = s2 * (1.0f / HID) - mu * mu;
  float rstd = rsqrtf(var + 1e-5f);
  float y0 = fmaxf((a0 - mu) * rstd * gamma[c] + beta[c], 0.0f);
  float y1 = fmaxf((a1 - mu) * rstd * gamma[c + 1] + beta[c + 1], 0.0f);
  if (L2) {
    uint32_t rh = *(const uint32_t*)(resh + (size_t)i * HID + c);
    uint32_t rl = *(const uint32_t*)(resl + (size_t)i * HID + c);
    y0 += bflo(rh) + bflo(rl);
    y1 += bfhi(rh) + bfhi(rl);
  }
  unsigned short ph0 = f2bf_rn(y0), ph1 = f2bf_rn(y1);
  uint32_t hw = (uint32_t)ph0 | ((uint32_t)ph1 << 16);
  uint32_t lw = (uint32_t)f2bf_rn(y0 - bf2f(ph0)) |
                ((uint32_t)f2bf_rn(y1 - bf2f(ph1)) << 16);
  *(uint32_t*)(oh + (size_t)i * HID + c) = hw;
  *(uint32_t*)(ol + (size_t)i * HID + c) = lw;
  if (L2) {
    float p[8];
#pragma unroll
    for (int h = 0; h < 8; ++h) p[h] = y0 * w[h][c] + y1 * w[h][c + 1];
#pragma unroll
    for (int m = 32; m >= 1; m >>= 1) {
#pragma unroll
      for (int h = 0; h < 8; ++h) p[h] += __shfl_xor(p[h], m);
    }
    if (lane == 0) {
      a_s[i * 4 + 0] = p[0]; a_s[i * 4 + 1] = p[1];
      a_s[i * 4 + 2] = p[2]; a_s[i * 4 + 3] = p[3];
      a_d[i * 4 + 0] = p[4]; a_d[i * 4 + 1] = p[5];
      a_d[i * 4 + 2] = p[6]; a_d[i * 4 + 3] = p[7];
    }
  }
}

// ---------------- fold Wgat into attention vectors ----------------
__global__ __launch_bounds__(256) void k_wprep(const float* __restrict__ Wgat,
                                               const float* __restrict__ att_src,
                                               const float* __restrict__ att_dst,
                                               float* __restrict__ waT) {
  int t = blockIdx.x * blockDim.x + threadIdx.x;  // 0..1023
  if (t >= 1024) return;
  int p = t >> 7, k = t & 127;
  int h = p & 3;
  const float* av = (p < 4 ? att_src : att_dst) + h * HID;
  const float* wrow = Wgat + (size_t)k * GATD + h * HID;
  float s = 0.f;
#pragma unroll 4
  for (int c = 0; c < HID; ++c) s = fmaf(wrow[c], av[c], s);
  waT[t] = s;
}

// ---------------- GAT softmax-aggregate: alpha precompute + gather loop ----------------
__global__ __launch_bounds__(256) void k_gat_agg(const unsigned short* __restrict__ xwgb,
                                                 const float* __restrict__ a_s,
                                                 const float* __restrict__ a_d,
                                                 const int* __restrict__ rowp,
                                                 const int* __restrict__ colsrc,
                                                 const float* __restrict__ bias,
                                                 float* __restrict__ alf,
                                                 unsigned short* __restrict__ gath,
                                                 unsigned short* __restrict__ gatl,
                                                 int n) {
  const int lane = threadIdx.x & 63;
  const int i = blockIdx.x * 4 + (threadIdx.x >> 6);
  if (i >= n) return;
  const float4 adv = *(const float4*)(a_d + i * 4);
  const float4 asv = *(const float4*)(a_s + i * 4);
  float es0 = lrelu02(asv.x + adv.x);
  float es1 = lrelu02(asv.y + adv.y);
  float es2 = lrelu02(asv.z + adv.z);
  float es3 = lrelu02(asv.w + adv.w);
  const int e0 = rowp[i], e1 = rowp[i + 1];
  float m0 = es0, m1 = es1, m2 = es2, m3 = es3;
  for (int j = e0 + lane; j < e1; j += 64) {
    int s = colsrc[j];
    const float4 av = *(const float4*)(a_s + s * 4);
    m0 = fmaxf(m0, lrelu02(av.x + adv.x));
    m1 = fmaxf(m1, lrelu02(av.y + adv.y));
    m2 = fmaxf(m2, lrelu02(av.z + adv.z));
    m3 = fmaxf(m3, lrelu02(av.w + adv.w));
  }
#pragma unroll
  for (int m = 32; m >= 1; m >>= 1) {
    m0 = fmaxf(m0, __shfl_xor(m0, m));
    m1 = fmaxf(m1, __shfl_xor(m1, m));
    m2 = fmaxf(m2, __shfl_xor(m2, m));
    m3 = fmaxf(m3, __shfl_xor(m3, m));
  }
  float d0 = 0.f, d1 = 0.f, d2 = 0.f, d3 = 0.f;
  for (int j = e0 + lane; j < e1; j += 64) {
    int s = colsrc[j];
    const float4 av = *(const float4*)(a_s + s * 4);
    d0 += __expf(lrelu02(av.x + adv.x) - m0);
    d1 += __expf(lrelu02(av.y + adv.y) - m1);
    d2 += __expf(lrelu02(av.z + adv.z) - m2);
    d3 += __expf(lrelu02(av.w + adv.w) - m3);
  }
#pragma unroll
  for (int m = 32; m >= 1; m >>= 1) {
    d0 += __shfl_xor(d0, m);
    d1 += __shfl_xor(d1, m);
    d2 += __shfl_xor(d2, m);
    d3 += __shfl_xor(d3, m);
  }
  d0 += __expf(es0 - m0);
  d1 += __expf(es1 - m1);
  d2 += __expf(es2 - m2);
  d3 += __expf(es3 - m3);
  const float inv0 = 1.0f / d0, inv1 = 1.0f / d1, inv2 = 1.0f / d2, inv3 = 1.0f / d3;
  for (int j = e0 + lane; j < e1; j += 64) {
    int s = colsrc[j];
    const float4 av = *(const float4*)(a_s + s * 4);
    float4 al4 = make_float4(__expf(lrelu02(av.x + adv.x) - m0) * inv0,
                             __expf(lrelu02(av.y + adv.y) - m1) * inv1,
                             __expf(lrelu02(av.z + adv.z) - m2) * inv2,
                             __expf(lrelu02(av.w + adv.w) - m3) * inv3);
    *(float4*)(alf + (size_t)j * 4) = al4;
  }
  const int col = lane * 8;
  const int h = lane >> 4;
  const float mh = (h < 2) ? (h == 0 ? m0 : m1) : (h == 2 ? m2 : m3);
  const float invh = (h < 2) ? (h == 0 ? inv0 : inv1) : (h == 2 ? inv2 : inv3);
  const float esh = (h < 2) ? (h == 0 ? es0 : es1) : (h == 2 ? es2 : es3);
  const float aself = __expf(esh - mh) * invh;
  uint4 u = *(const uint4*)(xwgb + (size_t)i * GATD + col);
  float4 acc0 = make_float4(bflo(u.x) * aself, bfhi(u.x) * aself,
                            bflo(u.y) * aself, bfhi(u.y) * aself);
  float4 acc1 = make_float4(bflo(u.z) * aself, bfhi(u.z) * aself,
                            bflo(u.w) * aself, bfhi(u.w) * aself);
  for (int j = e0; j < e1; ++j) {
    int s = colsrc[j];
    float al = alf[(size_t)j * 4 + h];
    uint4 w = *(const uint4*)(xwgb + (size_t)s * GATD + col);
    acc0.x = fmaf(bflo(w.x), al, acc0.x); acc0.y = fmaf(bfhi(w.x), al, acc0.y);
    acc0.z = fmaf(bflo(w.y), al, acc0.z); acc0.w = fmaf(bfhi(w.y), al, acc0.w);
    acc1.x = fmaf(bflo(w.z), al, acc1.x); acc1.y = fmaf(bfhi(w.z), al, acc1.y);
    acc1.z = fmaf(bflo(w.w), al, acc1.w * 0.f + acc1.z); acc1.w = fmaf(bfhi(w.w), al, acc1.w);
  }
  const float4* bp = (const float4*)(bias + col);
  float4 b0 = bp[0], b1 = bp[1];
  float vv[8] = {acc0.x + b0.x, acc0.y + b0.y, acc0.z + b0.z, acc0.w + b0.w,
                 acc1.x + b1.x, acc1.y + b1.y, acc1.z + b1.z, acc1.w + b1.w};
  uint32_t hv[4], lv[4];
#pragma unroll
  for (int q = 0; q < 4; ++q) {
    unsigned short ha = f2bf_rn(vv[2 * q]), hb = f2bf_rn(vv[2 * q + 1]);
    unsigned short la = f2bf_rn(vv[2 * q] - bf2f(ha));
    unsigned short lb = f2bf_rn(vv[2 * q + 1] - bf2f(hb));
    hv[q] = (uint32_t)ha | ((uint32_t)hb << 16);
    lv[q] = (uint32_t)la | ((uint32_t)lb << 16);
  }
  *(uint4*)(gath + (size_t)i * GATD + col) = make_uint4(hv[0], hv[1], hv[2], hv[3]);
  *(uint4*)(gatl + (size_t)i * GATD + col) = make_uint4(lv[0], lv[1], lv[2], lv[3]);
}

extern "C" void kernel_launch(void* const* d_in, const int* in_sizes, int n_in,
                              void* d_out, int out_size, void* d_ws, size_t ws_size,
                              hipStream_t stream) {
  const float* x = (const float*)d_in[0];
  const int* ei = (const int*)d_in[1];
  const float* Win = (const float*)d_in[2];
  const float* bin = (const float*)d_in[3];
  const float* Wg1 = (const float*)d_in[4];
  const float* bg1 = (const float*)d_in[5];
  const float* g1g = (const float*)d_in[6];
  const float* g1b = (const float*)d_in[7];
  const float* Wg2 = (const float*)d_in[8];
  const float* bg2 = (const float*)d_in[9];
  const float* g2g = (const float*)d_in[10];
  const float* g2b = (const float*)d_in[11];
  const float* Wgat = (const float*)d_in[12];
  const float* att_s = (const float*)d_in[13];
  const float* att_d = (const float*)d_in[14];
  const float* bgat = (const float*)d_in[15];
  const float* Wao = (const float*)d_in[16];
  const float* bao = (const float*)d_in[17];
  const float* Wout = (const float*)d_in[18];
  const float* bout = (const float*)d_in[19];

  const int N = in_sizes[0] / 256;
  const int E = in_sizes[1] / 2;
  const int* src = ei;
  const int* dst = ei + E;

  // ---- workspace layout (bytes), ~211 MB ----
  char* base = (char*)d_ws;
  size_t off = 0;
  unsigned short* xh = (unsigned short*)(base + off);  off += (size_t)N * 256 * 2;
  unsigned short* xl = (unsigned short*)(base + off);  off += (size_t)N * 256 * 2;
  unsigned short* h0h = (unsigned short*)(base + off); off += (size_t)N * HID * 2;
  unsigned short* h0l = (unsigned short*)(base + off); off += (size_t)N * HID * 2;
  unsigned short* x1h = (unsigned short*)(base + off); off += (size_t)N * HID * 2;
  unsigned short* x1l = (unsigned short*)(base + off); off += (size_t)N * HID * 2;
  unsigned short* gath = xh;   // dead by GAT agg
  unsigned short* gatl = h0h;  // dead by GAT agg
  float* xw = (float*)(base + off);                    off += (size_t)N * HID * 4;
  float* alf = xw;             // xw dead after 2nd gcn_agg; E*4 floats <= N*128
  unsigned short* x2h = (unsigned short*)(base + off); off += (size_t)N * HID * 2;
  unsigned short* x2l = (unsigned short*)(base + off); off += (size_t)N * HID * 2;
  unsigned short* atth = x2h;  // reuse after Wgat GEMM
  unsigned short* attl = x2l;
  unsigned short* xwgb = (unsigned short*)(base + off); off += (size_t)N * GATD * 2;
  float* dinv = (float*)(base + off);                  off += (size_t)N * 4;
  float* a_s = (float*)(base + off);                   off += (size_t)N * 16;
  float* a_d = (float*)(base + off);                   off += (size_t)N * 16;
  float* waT = (float*)(base + off);                   off += 4096;
  unsigned short *WinTh, *WinTl, *Wg1Th, *Wg1Tl, *Wg2Th, *Wg2Tl;
  unsigned short *WgatTh, *WgatTl, *WaoTh, *WaoTl, *WoutTh, *WoutTl;
  WinTh = (unsigned short*)(base + off);  off += 256 * 128 * 2;
  WinTl = (unsigned short*)(base + off);  off += 256 * 128 * 2;
  Wg1Th = (unsigned short*)(base + off);  off += 128 * 128 * 2;
  Wg1Tl = (unsigned short*)(base + off);  off += 128 * 128 * 2;
  Wg2Th = (unsigned short*)(base + off);  off += 128 * 128 * 2;
  Wg2Tl = (unsigned short*)(base + off);  off += 128 * 128 * 2;
  WgatTh = (unsigned short*)(base + off); off += 128 * 512 * 2;
  WgatTl = (unsigned short*)(base + off); off += 128 * 512 * 2;
  WaoTh = (unsigned short*)(base + off);  off += 512 * 128 * 2;
  WaoTl = (unsigned short*)(base + off);  off += 512 * 128 * 2;
  WoutTh = (unsigned short*)(base + off); off += 128 * 64 * 2;
  WoutTl = (unsigned short*)(base + off); off += 128 * 64 * 2;
  int* rowp = (int*)(base + off);   off += (size_t)(N + 1) * 4;
  int* colsrc = (int*)(base + off); off += (size_t)E * 4;
  const int nb2 = (N + 1023) / 1024;
  int* bsum = (int*)(base + off);   off += (size_t)(nb2 + 2) * 4;
  int* cnt = (int*)xwgb;  // alias: dead before xwgb is written
  int* cur = cnt + N;

  const int eb = (E + TPB - 1) / TPB;
  const int zb = (2 * N + TPB - 1) / TPB;
  const int ab = (N + 3) / 4;
  const int gm = (N + 63) / 64;

  // CSR + prep
  k_zero<<<zb, TPB, 0, stream>>>(cnt, 2 * N);
  k_hist<<<eb, TPB, 0, stream>>>(dst, cnt, E);
  k_scan_blk<<<nb2, 256, 0, stream>>>(cnt, rowp, bsum, dinv, N);
  k_scan_top<<<1, 256, 0, stream>>>(bsum, nb2);
  k_scan_add<<<(N + 255) / 256, 256, 0, stream>>>(rowp, bsum, N, nb2);
  k_fill<<<eb, TPB, 0, stream>>>(src, dst, rowp, cur, colsrc, E);
  k_wprep<<<4, 256, 0, stream>>>(Wgat, att_s, att_d, waT);
  k_splitx<<<(int)(((long)N * 256 + 255) / 256), 256, 0, stream>>>(x, xh, xl, (long)N * 256);
  k_splitw_all<<<(204800 + 255) / 256, 256, 0, stream>>>(
      Win, Wg1, Wg2, Wgat, Wao, Wout, WinTh, WinTl, Wg1Th, Wg1Tl, Wg2Th, Wg2Tl,
      WgatTh, WgatTl, WaoTh, WaoTl, WoutTh, WoutTl);

  // h0 = relu(x @ Win + bin) -> planes       [K=256, 1 strip of 128]
  k_gemm5<256, 64, 128, true, true, 2><<<dim3(gm, 1), 256, 0, stream>>>(
      xh, xl, WinTh, WinTl, bin, h0h, h0l, N, 128);
  // GCN layer 1                               [K=128]
  k_gemm5<128, 64, 128, false, false, 0><<<dim3(gm, 1), 256, 0, stream>>>(
      h0h, h0l, Wg1Th, Wg1Tl, nullptr, xw, nullptr, N, 128);
  k_gcn_agg<false><<<ab, 256, 0, stream>>>(xw, dinv, rowp, colsrc, bg1, g1g, g1b,
                                           nullptr, nullptr, x1h, x1l,
                                           nullptr, nullptr, nullptr, N);
  // GCN layer 2 (+residual, +fused GAT logits)
  k_gemm5<128, 64, 128, false, false, 0><<<dim3(gm, 1), 256, 0, stream>>>(
      x1h, x1l, Wg2Th, Wg2Tl, nullptr, xw, nullptr, N, 128);
  k_gcn_agg<true><<<ab, 256, 0, stream>>>(xw, dinv, rowp, colsrc, bg2, g2g, g2b,
                                          x1h, x1l, x2h, x2l, waT, a_s, a_d, N);
  // GAT: xwgb = bf16(x2 @ Wgat)               [NC=512, 4 strips of 128]
  k_gemm5<128, 64, 128, false, false, 1><<<dim3(gm, 4), 256, 0, stream>>>(
      x2h, x2l, WgatTh, WgatTl, nullptr, xwgb, nullptr, N, 512);
  // softmax-aggregate -> gat planes
  k_gat_agg<<<ab, 256, 0, stream>>>(xwgb, a_s, a_d, rowp, colsrc, bgat, alf, gath, gatl, N);
  // att = relu(gat @ Wao + bao) -> planes     [K=512, 8 chunks]
  k_gemm5<512, 64, 128, true, true, 2><<<dim3(gm, 1), 256, 0, stream>>>(
      gath, gatl, WaoTh, WaoTl, bao, atth, attl, N, 128);
  // out = att @ Wout + bout (fp32)            [NC=64, KC=128]
  k_gemm5<128, 128, 64, false, true, 0><<<dim3(gm, 1), 256, 0, stream>>>(
      atth, attl, WoutTh, WoutTl, bout, d_out, nullptr, N, 64);
}

// Round 9
// 561.697 us; speedup vs baseline: 1.7644x; 1.1929x over previous
//
#include <hip/hip_runtime.h>
#include <hip/hip_bf16.h>
#include <cstddef>
#include <cstdint>

#define TPB 256
#define HID 128
#define GATD 512
#define HEADS 4

typedef __attribute__((ext_vector_type(8))) short bf16x8;
typedef __attribute__((ext_vector_type(4))) float f32x4;

__device__ __forceinline__ float lrelu02(float x) { return x > 0.0f ? x : 0.2f * x; }

__device__ __forceinline__ unsigned short f2bf_rn(float f) {
  uint32_t u = __float_as_uint(f);
  u += 0x7fff + ((u >> 16) & 1);
  return (unsigned short)(u >> 16);
}
__device__ __forceinline__ float bf2f(unsigned short h) {
  return __uint_as_float(((uint32_t)h) << 16);
}
__device__ __forceinline__ float bflo(uint32_t u) { return __uint_as_float(u << 16); }
__device__ __forceinline__ float bfhi(uint32_t u) { return __uint_as_float(u & 0xffff0000u); }

// ---------------- utility ----------------
__global__ void k_zero(int* __restrict__ p, int n) {
  int i = blockIdx.x * blockDim.x + threadIdx.x;
  if (i < n) p[i] = 0;
}

// ---------------- CSR build ----------------
__global__ void k_hist(const int* __restrict__ dst, int* __restrict__ cnt, int E) {
  int i = blockIdx.x * blockDim.x + threadIdx.x;
  if (i < E) atomicAdd(&cnt[dst[i]], 1);
}

__global__ __launch_bounds__(256) void k_scan_blk(const int* __restrict__ cnt,
                                                  int* __restrict__ rowp,
                                                  int* __restrict__ bsum,
                                                  float* __restrict__ dinv, int n) {
  __shared__ int wsum[4];
  const int tid = threadIdx.x, lane = tid & 63, wid = tid >> 6;
  const int base = blockIdx.x * 1024 + tid * 4;
  int v[4];
#pragma unroll
  for (int q = 0; q < 4; ++q) {
    int idx = base + q;
    v[q] = (idx < n) ? cnt[idx] : 0;
    if (idx < n) dinv[idx] = rsqrtf((float)(v[q] + 1));  // +1 self loop
  }
  int s = v[0] + v[1] + v[2] + v[3];
  int sc = s;
#pragma unroll
  for (int off = 1; off < 64; off <<= 1) {
    int t = __shfl_up(sc, off);
    if (lane >= off) sc += t;
  }
  if (lane == 63) wsum[wid] = sc;
  __syncthreads();
  int woff = 0;
#pragma unroll
  for (int w = 0; w < 4; ++w)
    if (w < wid) woff += wsum[w];
  int run = woff + sc - s;
#pragma unroll
  for (int q = 0; q < 4; ++q) {
    int idx = base + q;
    if (idx < n) rowp[idx] = run;
    run += v[q];
  }
  if (tid == 255) bsum[blockIdx.x] = woff + sc;
}

__global__ __launch_bounds__(256) void k_scan_top(int* __restrict__ bsum, int nb) {
  __shared__ int sm[256];
  const int tid = threadIdx.x;
  int v = (tid < nb) ? bsum[tid] : 0;
  sm[tid] = v;
  __syncthreads();
  for (int off = 1; off < 256; off <<= 1) {
    int t = (tid >= off) ? sm[tid - off] : 0;
    __syncthreads();
    sm[tid] += t;
    __syncthreads();
  }
  int incl = sm[tid];
  if (tid < nb) bsum[tid] = incl - v;
  if (tid == nb - 1) bsum[nb] = incl;
}

__global__ void k_scan_add(int* __restrict__ rowp, const int* __restrict__ bsum,
                           int n, int nb) {
  int i = blockIdx.x * blockDim.x + threadIdx.x;
  if (i < n) rowp[i] += bsum[i >> 10];
  if (i == 0) rowp[n] = bsum[nb];
}

__global__ void k_fill(const int* __restrict__ src, const int* __restrict__ dst,
                       const int* __restrict__ rowp, int* __restrict__ cur,
                       int* __restrict__ colsrc, int E) {
  int i = blockIdx.x * blockDim.x + threadIdx.x;
  if (i < E) {
    int d = dst[i];
    int pos = rowp[d] + atomicAdd(&cur[d], 1);
    colsrc[pos] = src[i];
  }
}

// ---------------- weight split (transposed hi/lo planes), one launch ----------------
__global__ void k_splitw_all(const float* __restrict__ Win, const float* __restrict__ Wg1,
                             const float* __restrict__ Wg2, const float* __restrict__ Wgat,
                             const float* __restrict__ Wao, const float* __restrict__ Wout,
                             unsigned short* __restrict__ WinTh, unsigned short* __restrict__ WinTl,
                             unsigned short* __restrict__ Wg1Th, unsigned short* __restrict__ Wg1Tl,
                             unsigned short* __restrict__ Wg2Th, unsigned short* __restrict__ Wg2Tl,
                             unsigned short* __restrict__ WgatTh, unsigned short* __restrict__ WgatTl,
                             unsigned short* __restrict__ WaoTh, unsigned short* __restrict__ WaoTl,
                             unsigned short* __restrict__ WoutTh, unsigned short* __restrict__ WoutTl) {
  int t = blockIdx.x * blockDim.x + threadIdx.x;
  const float* W;
  unsigned short *H, *L;
  int K, NC, r;
  if (t < 32768)       { W = Win;  H = WinTh;  L = WinTl;  K = 256; NC = 128; r = t; }
  else if (t < 49152)  { W = Wg1;  H = Wg1Th;  L = Wg1Tl;  K = 128; NC = 128; r = t - 32768; }
  else if (t < 65536)  { W = Wg2;  H = Wg2Th;  L = Wg2Tl;  K = 128; NC = 128; r = t - 49152; }
  else if (t < 131072) { W = Wgat; H = WgatTh; L = WgatTl; K = 128; NC = 512; r = t - 65536; }
  else if (t < 196608) { W = Wao;  H = WaoTh;  L = WaoTl;  K = 512; NC = 128; r = t - 131072; }
  else if (t < 204800) { W = Wout; H = WoutTh; L = WoutTl; K = 128; NC = 64;  r = t - 196608; }
  else return;
  int k = r / NC, n2 = r % NC;
  float v = W[r];
  unsigned short h = f2bf_rn(v);
  H[(size_t)n2 * K + k] = h;
  L[(size_t)n2 * K + k] = f2bf_rn(v - bf2f(h));
}

// ---------------- weight-stationary MFMA GEMM ----------------
// C = act(A @ W + bias); W as (BhT,BlT)[NC,KTOT] transposed hi/lo planes in LDS per chunk.
// AMODE 0: A = (Ah,Al) pre-split planes.  AMODE 1: Ah = fp32 A, split in registers.
// A fragments stream global->register (lane layout == MFMA A-frag layout).
// A*B ~= Ah*Bh + Ah*Bl + Al*Bh.  OUTM: 0=f32, 1=bf16, 2=hi/lo planes.
template <int KTOT, int KC, int NCB, bool RELU, bool BIAS, int OUTM, int AMODE>
__global__ __launch_bounds__(256) void k_gemm5(
    const unsigned short* __restrict__ Ah, const unsigned short* __restrict__ Al,
    const unsigned short* __restrict__ BhT, const unsigned short* __restrict__ BlT,
    const float* __restrict__ bias, void* __restrict__ Cv, void* __restrict__ Cv2,
    int M, int NC) {
  constexpr int NSUB = KC / 32;
  constexpr int NCHUNK = KTOT / KC;
  constexpr int NCF = NCB / 16;
  constexpr int UNITS = NSUB * 2 * 4 * NCB;  // 16B ds_write units per chunk
  __shared__ alignas(16) unsigned short Bs[NSUB][2][4][NCB][8];
  const int tid = threadIdx.x, lane = tid & 63, wid = tid >> 6;
  const int m0 = blockIdx.x * 64;
  const int n0 = blockIdx.y * NCB;
  const int fr = lane & 15, g = lane >> 4;
  const int arow = m0 + wid * 16 + fr;
  const bool aok = arow < M;
  const size_t abase = (size_t)arow * KTOT;

  f32x4 acc[NCF];
#pragma unroll
  for (int cf = 0; cf < NCF; ++cf) acc[cf] = (f32x4){0.f, 0.f, 0.f, 0.f};

  for (int c = 0; c < NCHUNK; ++c) {
    const int c0 = c * KC;
    if (c > 0) __syncthreads();  // previous chunk's reads done
#pragma unroll
    for (int it = 0; it < UNITS / 256; ++it) {
      const int u = tid + it * 256;
      const int n = u % NCB;
      int rest = u / NCB;
      const int kg = rest & 3;
      rest >>= 2;
      const int p = rest & 1;
      const int sub = rest >> 1;
      const unsigned short* sp =
          (p ? BlT : BhT) + (size_t)(n0 + n) * KTOT + c0 + sub * 32 + kg * 8;
      *(uint4*)&Bs[sub][p][kg][n][0] = *(const uint4*)sp;
    }
    __syncthreads();
#pragma unroll
    for (int sub = 0; sub < NSUB; ++sub) {
      const int kb = c0 + sub * 32 + g * 8;
      bf16x8 a_h = {}, a_l = {};
      if (aok) {
        if (AMODE == 0) {
          a_h = *(const bf16x8*)(Ah + abase + kb);
          a_l = *(const bf16x8*)(Al + abase + kb);
        } else {
          const float* Af = (const float*)Ah + abase + kb;
          float4 q0 = *(const float4*)Af;
          float4 q1 = *(const float4*)(Af + 4);
          float av[8] = {q0.x, q0.y, q0.z, q0.w, q1.x, q1.y, q1.z, q1.w};
          union { bf16x8 v; uint32_t u4[4]; } Hu, Lu;
#pragma unroll
          for (int q = 0; q < 4; ++q) {
            unsigned short h0 = f2bf_rn(av[2 * q]);
            unsigned short h1 = f2bf_rn(av[2 * q + 1]);
            unsigned short l0 = f2bf_rn(av[2 * q] - bf2f(h0));
            unsigned short l1 = f2bf_rn(av[2 * q + 1] - bf2f(h1));
            Hu.u4[q] = (uint32_t)h0 | ((uint32_t)h1 << 16);
            Lu.u4[q] = (uint32_t)l0 | ((uint32_t)l1 << 16);
          }
          a_h = Hu.v;
          a_l = Lu.v;
        }
      }
#pragma unroll
      for (int cf = 0; cf < NCF; ++cf) {
        bf16x8 b_h = *(const bf16x8*)&Bs[sub][0][g][cf * 16 + fr][0];
        bf16x8 b_l = *(const bf16x8*)&Bs[sub][1][g][cf * 16 + fr][0];
        acc[cf] = __builtin_amdgcn_mfma_f32_16x16x32_bf16(a_h, b_h, acc[cf], 0, 0, 0);
        acc[cf] = __builtin_amdgcn_mfma_f32_16x16x32_bf16(a_h, b_l, acc[cf], 0, 0, 0);
        acc[cf] = __builtin_amdgcn_mfma_f32_16x16x32_bf16(a_l, b_h, acc[cf], 0, 0, 0);
      }
    }
  }
  // ---- epilogue: D layout col=lane&15, row=(lane>>4)*4+r ----
#pragma unroll
  for (int cf = 0; cf < NCF; ++cf) {
    const int col = n0 + cf * 16 + fr;
    const float bv = BIAS ? bias[col] : 0.f;
#pragma unroll
    for (int r = 0; r < 4; ++r) {
      const int grow = m0 + wid * 16 + g * 4 + r;
      if (grow < M) {
        float v = acc[cf][r] + bv;
        if (RELU) v = fmaxf(v, 0.f);
        const size_t idx = (size_t)grow * NC + col;
        if (OUTM == 0) {
          ((float*)Cv)[idx] = v;
        } else if (OUTM == 1) {
          ((unsigned short*)Cv)[idx] = f2bf_rn(v);
        } else {
          unsigned short h = f2bf_rn(v);
          ((unsigned short*)Cv)[idx] = h;
          ((unsigned short*)Cv2)[idx] = f2bf_rn(v - bf2f(h));
        }
      }
    }
  }
}

// ---------------- GCN aggregate (bf16 gather) + bias + LN + ReLU (+residual, +GAT logits) ----------------
template <bool L2>
__global__ __launch_bounds__(256) void k_gcn_agg(
    const unsigned short* __restrict__ xwb, const float* __restrict__ dinv,
    const int* __restrict__ rowp, const int* __restrict__ colsrc,
    const float* __restrict__ bias, const float* __restrict__ gamma,
    const float* __restrict__ beta,
    const unsigned short* __restrict__ resh, const unsigned short* __restrict__ resl,
    unsigned short* __restrict__ oh, unsigned short* __restrict__ ol,
    const float* __restrict__ waT, float* __restrict__ a_s, float* __restrict__ a_d,
    int n) {
  __shared__ float w[8][HID];
  if (L2) {
    for (int t = threadIdx.x; t < 8 * HID; t += 256) ((float*)w)[t] = waT[t];
    __syncthreads();
  }
  const int lane = threadIdx.x & 63;
  const int i = blockIdx.x * 4 + (threadIdx.x >> 6);
  if (i >= n) return;
  const float di = dinv[i];
  const int c = lane * 2;
  uint32_t v0 = *(const uint32_t*)(xwb + (size_t)i * HID + c);
  float a0 = bflo(v0) * di * di, a1 = bfhi(v0) * di * di;  // self loop
  float b0 = 0.f, b1 = 0.f;
  const int e0 = rowp[i], e1 = rowp[i + 1];
  int j = e0;
  for (; j + 1 < e1; j += 2) {
    int s0 = colsrc[j], s1 = colsrc[j + 1];
    float w0 = dinv[s0] * di, w1 = dinv[s1] * di;
    uint32_t u0 = *(const uint32_t*)(xwb + (size_t)s0 * HID + c);
    uint32_t u1 = *(const uint32_t*)(xwb + (size_t)s1 * HID + c);
    a0 = fmaf(bflo(u0), w0, a0);
    a1 = fmaf(bfhi(u0), w0, a1);
    b0 = fmaf(bflo(u1), w1, b0);
    b1 = fmaf(bfhi(u1), w1, b1);
  }
  if (j < e1) {
    int s0 = colsrc[j];
    float w0 = dinv[s0] * di;
    uint32_t u0 = *(const uint32_t*)(xwb + (size_t)s0 * HID + c);
    a0 = fmaf(bflo(u0), w0, a0);
    a1 = fmaf(bfhi(u0), w0, a1);
  }
  a0 += b0;
  a1 += b1;
  a0 += bias[c];
  a1 += bias[c + 1];
  float s1 = a0 + a1, s2 = a0 * a0 + a1 * a1;
#pragma unroll
  for (int m = 32; m >= 1; m >>= 1) {
    s1 += __shfl_xor(s1, m);
    s2 += __shfl_xor(s2, m);
  }
  float mu = s1 * (1.0f / HID);
  float var = s2 * (1.0f / HID) - mu * mu;
  float rstd = rsqrtf(var + 1e-5f);
  float y0 = fmaxf((a0 - mu) * rstd * gamma[c] + beta[c], 0.0f);
  float y1 = fmaxf((a1 - mu) * rstd * gamma[c + 1] + beta[c + 1], 0.0f);
  if (L2) {
    uint32_t rh = *(const uint32_t*)(resh + (size_t)i * HID + c);
    uint32_t rl = *(const uint32_t*)(resl + (size_t)i * HID + c);
    y0 += bflo(rh) + bflo(rl);
    y1 += bfhi(rh) + bfhi(rl);
  }
  unsigned short ph0 = f2bf_rn(y0), ph1 = f2bf_rn(y1);
  uint32_t hw = (uint32_t)ph0 | ((uint32_t)ph1 << 16);
  uint32_t lw = (uint32_t)f2bf_rn(y0 - bf2f(ph0)) |
                ((uint32_t)f2bf_rn(y1 - bf2f(ph1)) << 16);
  *(uint32_t*)(oh + (size_t)i * HID + c) = hw;
  *(uint32_t*)(ol + (size_t)i * HID + c) = lw;
  if (L2) {
    float p[8];
#pragma unroll
    for (int h = 0; h < 8; ++h) p[h] = y0 * w[h][c] + y1 * w[h][c + 1];
#pragma unroll
    for (int m = 32; m >= 1; m >>= 1) {
#pragma unroll
      for (int h = 0; h < 8; ++h) p[h] += __shfl_xor(p[h], m);
    }
    if (lane == 0) {
      a_s[i * 4 + 0] = p[0]; a_s[i * 4 + 1] = p[1];
      a_s[i * 4 + 2] = p[2]; a_s[i * 4 + 3] = p[3];
      a_d[i * 4 + 0] = p[4]; a_d[i * 4 + 1] = p[5];
      a_d[i * 4 + 2] = p[6]; a_d[i * 4 + 3] = p[7];
    }
  }
}

// ---------------- fold Wgat into attention vectors ----------------
__global__ __launch_bounds__(256) void k_wprep(const float* __restrict__ Wgat,
                                               const float* __restrict__ att_src,
                                               const float* __restrict__ att_dst,
                                               float* __restrict__ waT) {
  int t = blockIdx.x * blockDim.x + threadIdx.x;  // 0..1023
  if (t >= 1024) return;
  int p = t >> 7, k = t & 127;
  int h = p & 3;
  const float* av = (p < 4 ? att_src : att_dst) + h * HID;
  const float* wrow = Wgat + (size_t)k * GATD + h * HID;
  float s = 0.f;
#pragma unroll 4
  for (int c = 0; c < HID; ++c) s = fmaf(wrow[c], av[c], s);
  waT[t] = s;
}

// ---------------- GAT softmax-aggregate (wave/node), bf16 table, plane output ----------------
__global__ __launch_bounds__(256) void k_gat_agg(const unsigned short* __restrict__ xwgb,
                                                 const float* __restrict__ a_s,
                                                 const float* __restrict__ a_d,
                                                 const int* __restrict__ rowp,
                                                 const int* __restrict__ colsrc,
                                                 const float* __restrict__ bias,
                                                 unsigned short* __restrict__ gath,
                                                 unsigned short* __restrict__ gatl,
                                                 int n) {
  const int lane = threadIdx.x & 63;
  const int i = blockIdx.x * 4 + (threadIdx.x >> 6);
  if (i >= n) return;
  const float4 adv = *(const float4*)(a_d + i * 4);
  const float4 asv = *(const float4*)(a_s + i * 4);
  float es0 = lrelu02(asv.x + adv.x);
  float es1 = lrelu02(asv.y + adv.y);
  float es2 = lrelu02(asv.z + adv.z);
  float es3 = lrelu02(asv.w + adv.w);
  const int e0 = rowp[i], e1 = rowp[i + 1];
  // pass 1: max
  float m0 = es0, m1 = es1, m2 = es2, m3 = es3;
  for (int j = e0 + lane; j < e1; j += 64) {
    int s = colsrc[j];
    const float4 av = *(const float4*)(a_s + s * 4);
    m0 = fmaxf(m0, lrelu02(av.x + adv.x));
    m1 = fmaxf(m1, lrelu02(av.y + adv.y));
    m2 = fmaxf(m2, lrelu02(av.z + adv.z));
    m3 = fmaxf(m3, lrelu02(av.w + adv.w));
  }
#pragma unroll
  for (int m = 32; m >= 1; m >>= 1) {
    m0 = fmaxf(m0, __shfl_xor(m0, m));
    m1 = fmaxf(m1, __shfl_xor(m1, m));
    m2 = fmaxf(m2, __shfl_xor(m2, m));
    m3 = fmaxf(m3, __shfl_xor(m3, m));
  }
  // pass 2: denom
  float d0 = 0.f, d1 = 0.f, d2 = 0.f, d3 = 0.f;
  for (int j = e0 + lane; j < e1; j += 64) {
    int s = colsrc[j];
    const float4 av = *(const float4*)(a_s + s * 4);
    d0 += __expf(lrelu02(av.x + adv.x) - m0);
    d1 += __expf(lrelu02(av.y + adv.y) - m1);
    d2 += __expf(lrelu02(av.z + adv.z) - m2);
    d3 += __expf(lrelu02(av.w + adv.w) - m3);
  }
#pragma unroll
  for (int m = 32; m >= 1; m >>= 1) {
    d0 += __shfl_xor(d0, m);
    d1 += __shfl_xor(d1, m);
    d2 += __shfl_xor(d2, m);
    d3 += __shfl_xor(d3, m);
  }
  d0 += __expf(es0 - m0);
  d1 += __expf(es1 - m1);
  d2 += __expf(es2 - m2);
  d3 += __expf(es3 - m3);
  const float inv0 = 1.0f / d0, inv1 = 1.0f / d1, inv2 = 1.0f / d2, inv3 = 1.0f / d3;
  const int col = lane * 8;
  const int h = lane >> 4;
  const float mh = (h < 2) ? (h == 0 ? m0 : m1) : (h == 2 ? m2 : m3);
  const float invh = (h < 2) ? (h == 0 ? inv0 : inv1) : (h == 2 ? inv2 : inv3);
  const float adh = (h < 2) ? (h == 0 ? adv.x : adv.y) : (h == 2 ? adv.z : adv.w);
  const float esh = (h < 2) ? (h == 0 ? es0 : es1) : (h == 2 ? es2 : es3);
  const float aself = __expf(esh - mh) * invh;
  // pass 3: alpha-weighted bf16 message accumulation, 2-edge unroll, dual chains
  uint4 u = *(const uint4*)(xwgb + (size_t)i * GATD + col);
  float4 accA0 = make_float4(bflo(u.x) * aself, bfhi(u.x) * aself,
                             bflo(u.y) * aself, bfhi(u.y) * aself);
  float4 accA1 = make_float4(bflo(u.z) * aself, bfhi(u.z) * aself,
                             bflo(u.w) * aself, bfhi(u.w) * aself);
  float4 accB0 = make_float4(0.f, 0.f, 0.f, 0.f);
  float4 accB1 = make_float4(0.f, 0.f, 0.f, 0.f);
  int j = e0;
  for (; j + 1 < e1; j += 2) {
    int s0 = colsrc[j], s1 = colsrc[j + 1];
    float al0 = __expf(lrelu02(a_s[s0 * 4 + h] + adh) - mh) * invh;
    float al1 = __expf(lrelu02(a_s[s1 * 4 + h] + adh) - mh) * invh;
    uint4 w0 = *(const uint4*)(xwgb + (size_t)s0 * GATD + col);
    uint4 w1 = *(const uint4*)(xwgb + (size_t)s1 * GATD + col);
    accA0.x = fmaf(bflo(w0.x), al0, accA0.x); accA0.y = fmaf(bfhi(w0.x), al0, accA0.y);
    accA0.z = fmaf(bflo(w0.y), al0, accA0.z); accA0.w = fmaf(bfhi(w0.y), al0, accA0.w);
    accA1.x = fmaf(bflo(w0.z), al0, accA1.x); accA1.y = fmaf(bfhi(w0.z), al0, accA1.y);
    accA1.z = fmaf(bflo(w0.w), al0, accA1.z); accA1.w = fmaf(bfhi(w0.w), al0, accA1.w);
    accB0.x = fmaf(bflo(w1.x), al1, accB0.x); accB0.y = fmaf(bfhi(w1.x), al1, accB0.y);
    accB0.z = fmaf(bflo(w1.y), al1, accB0.z); accB0.w = fmaf(bfhi(w1.y), al1, accB0.w);
    accB1.x = fmaf(bflo(w1.z), al1, accB1.x); accB1.y = fmaf(bfhi(w1.z), al1, accB1.y);
    accB1.z = fmaf(bflo(w1.w), al1, accB1.z); accB1.w = fmaf(bfhi(w1.w), al1, accB1.w);
  }
  if (j < e1) {
    int s0 = colsrc[j];
    float al0 = __expf(lrelu02(a_s[s0 * 4 + h] + adh) - mh) * invh;
    uint4 w0 = *(const uint4*)(xwgb + (size_t)s0 * GATD + col);
    accA0.x = fmaf(bflo(w0.x), al0, accA0.x); accA0.y = fmaf(bfhi(w0.x), al0, accA0.y);
    accA0.z = fmaf(bflo(w0.y), al0, accA0.z); accA0.w = fmaf(bfhi(w0.y), al0, accA0.w);
    accA1.x = fmaf(bflo(w0.z), al0, accA1.x); accA1.y = fmaf(bfhi(w0.z), al0, accA1.y);
    accA1.z = fmaf(bflo(w0.w), al0, accA1.z); accA1.w = fmaf(bfhi(w0.w), al0, accA1.w);
  }
  accA0.x += accB0.x; accA0.y += accB0.y; accA0.z += accB0.z; accA0.w += accB0.w;
  accA1.x += accB1.x; accA1.y += accB1.y; accA1.z += accB1.z; accA1.w += accB1.w;
  const float4* bp = (const float4*)(bias + col);
  float4 b0 = bp[0], b1 = bp[1];
  float vv[8] = {accA0.x + b0.x, accA0.y + b0.y, accA0.z + b0.z, accA0.w + b0.w,
                 accA1.x + b1.x, accA1.y + b1.y, accA1.z + b1.z, accA1.w + b1.w};
  uint32_t hv[4], lv[4];
#pragma unroll
  for (int q = 0; q < 4; ++q) {
    unsigned short ha = f2bf_rn(vv[2 * q]), hb = f2bf_rn(vv[2 * q + 1]);
    unsigned short la = f2bf_rn(vv[2 * q] - bf2f(ha));
    unsigned short lb = f2bf_rn(vv[2 * q + 1] - bf2f(hb));
    hv[q] = (uint32_t)ha | ((uint32_t)hb << 16);
    lv[q] = (uint32_t)la | ((uint32_t)lb << 16);
  }
  *(uint4*)(gath + (size_t)i * GATD + col) = make_uint4(hv[0], hv[1], hv[2], hv[3]);
  *(uint4*)(gatl + (size_t)i * GATD + col) = make_uint4(lv[0], lv[1], lv[2], lv[3]);
}

extern "C" void kernel_launch(void* const* d_in, const int* in_sizes, int n_in,
                              void* d_out, int out_size, void* d_ws, size_t ws_size,
                              hipStream_t stream) {
  const float* x = (const float*)d_in[0];
  const int* ei = (const int*)d_in[1];
  const float* Win = (const float*)d_in[2];
  const float* bin = (const float*)d_in[3];
  const float* Wg1 = (const float*)d_in[4];
  const float* bg1 = (const float*)d_in[5];
  const float* g1g = (const float*)d_in[6];
  const float* g1b = (const float*)d_in[7];
  const float* Wg2 = (const float*)d_in[8];
  const float* bg2 = (const float*)d_in[9];
  const float* g2g = (const float*)d_in[10];
  const float* g2b = (const float*)d_in[11];
  const float* Wgat = (const float*)d_in[12];
  const float* att_s = (const float*)d_in[13];
  const float* att_d = (const float*)d_in[14];
  const float* bgat = (const float*)d_in[15];
  const float* Wao = (const float*)d_in[16];
  const float* bao = (const float*)d_in[17];
  const float* Wout = (const float*)d_in[18];
  const float* bout = (const float*)d_in[19];

  const int N = in_sizes[0] / 256;
  const int E = in_sizes[1] / 2;
  const int* src = ei;
  const int* dst = ei + E;

  // ---- workspace layout (bytes), ~195 MB ----
  char* base = (char*)d_ws;
  size_t off = 0;
  unsigned short* gath = (unsigned short*)(base + off); off += (size_t)N * GATD * 2;
  unsigned short* h0h = (unsigned short*)(base + off); off += (size_t)N * HID * 2;
  unsigned short* h0l = (unsigned short*)(base + off); off += (size_t)N * HID * 2;
  unsigned short* x1h = (unsigned short*)(base + off); off += (size_t)N * HID * 2;
  unsigned short* x1l = (unsigned short*)(base + off); off += (size_t)N * HID * 2;
  unsigned short* gatl = h0h;  // h0|x1 planes (51.2MB contig) dead by GAT agg
  unsigned short* xwb = (unsigned short*)(base + off); off += (size_t)N * HID * 2;
  unsigned short* x2h = (unsigned short*)(base + off); off += (size_t)N * HID * 2;
  unsigned short* x2l = (unsigned short*)(base + off); off += (size_t)N * HID * 2;
  unsigned short* atth = x2h;  // reuse after Wgat GEMM
  unsigned short* attl = x2l;
  unsigned short* xwgb = (unsigned short*)(base + off); off += (size_t)N * GATD * 2;
  float* dinv = (float*)(base + off);                  off += (size_t)N * 4;
  float* a_s = (float*)(base + off);                   off += (size_t)N * 16;
  float* a_d = (float*)(base + off);                   off += (size_t)N * 16;
  float* waT = (float*)(base + off);                   off += 4096;
  unsigned short *WinTh, *WinTl, *Wg1Th, *Wg1Tl, *Wg2Th, *Wg2Tl;
  unsigned short *WgatTh, *WgatTl, *WaoTh, *WaoTl, *WoutTh, *WoutTl;
  WinTh = (unsigned short*)(base + off);  off += 256 * 128 * 2;
  WinTl = (unsigned short*)(base + off);  off += 256 * 128 * 2;
  Wg1Th = (unsigned short*)(base + off);  off += 128 * 128 * 2;
  Wg1Tl = (unsigned short*)(base + off);  off += 128 * 128 * 2;
  Wg2Th = (unsigned short*)(base + off);  off += 128 * 128 * 2;
  Wg2Tl = (unsigned short*)(base + off);  off += 128 * 128 * 2;
  WgatTh = (unsigned short*)(base + off); off += 128 * 512 * 2;
  WgatTl = (unsigned short*)(base + off); off += 128 * 512 * 2;
  WaoTh = (unsigned short*)(base + off);  off += 512 * 128 * 2;
  WaoTl = (unsigned short*)(base + off);  off += 512 * 128 * 2;
  WoutTh = (unsigned short*)(base + off); off += 128 * 64 * 2;
  WoutTl = (unsigned short*)(base + off); off += 128 * 64 * 2;
  int* rowp = (int*)(base + off);   off += (size_t)(N + 1) * 4;
  int* colsrc = (int*)(base + off); off += (size_t)E * 4;
  const int nb2 = (N + 1023) / 1024;
  int* bsum = (int*)(base + off);   off += (size_t)(nb2 + 2) * 4;
  int* cnt = (int*)xwgb;  // alias: dead before xwgb is written
  int* cur = cnt + N;

  const int eb = (E + TPB - 1) / TPB;
  const int zb = (2 * N + TPB - 1) / TPB;
  const int ab = (N + 3) / 4;
  const int gm = (N + 63) / 64;

  // CSR + prep
  k_zero<<<zb, TPB, 0, stream>>>(cnt, 2 * N);
  k_hist<<<eb, TPB, 0, stream>>>(dst, cnt, E);
  k_scan_blk<<<nb2, 256, 0, stream>>>(cnt, rowp, bsum, dinv, N);
  k_scan_top<<<1, 256, 0, stream>>>(bsum, nb2);
  k_scan_add<<<(N + 255) / 256, 256, 0, stream>>>(rowp, bsum, N, nb2);
  k_fill<<<eb, TPB, 0, stream>>>(src, dst, rowp, cur, colsrc, E);
  k_wprep<<<4, 256, 0, stream>>>(Wgat, att_s, att_d, waT);
  k_splitw_all<<<(204800 + 255) / 256, 256, 0, stream>>>(
      Win, Wg1, Wg2, Wgat, Wao, Wout, WinTh, WinTl, Wg1Th, Wg1Tl, Wg2Th, Wg2Tl,
      WgatTh, WgatTl, WaoTh, WaoTl, WoutTh, WoutTl);

  // h0 = relu(x @ Win + bin) -> planes    [fp32 A split in regs]
  k_gemm5<256, 64, 128, true, true, 2, 1><<<dim3(gm, 1), 256, 0, stream>>>(
      (const unsigned short*)x, nullptr, WinTh, WinTl, bin, h0h, h0l, N, 128);
  // GCN layer 1: xwb = bf16(h0 @ Wg1)
  k_gemm5<128, 64, 128, false, false, 1, 0><<<dim3(gm, 1), 256, 0, stream>>>(
      h0h, h0l, Wg1Th, Wg1Tl, nullptr, xwb, nullptr, N, 128);
  k_gcn_agg<false><<<ab, 256, 0, stream>>>(xwb, dinv, rowp, colsrc, bg1, g1g, g1b,
                                           nullptr, nullptr, x1h, x1l,
                                           nullptr, nullptr, nullptr, N);
  // GCN layer 2 (+residual, +fused GAT logits)
  k_gemm5<128, 64, 128, false, false, 1, 0><<<dim3(gm, 1), 256, 0, stream>>>(
      x1h, x1l, Wg2Th, Wg2Tl, nullptr, xwb, nullptr, N, 128);
  k_gcn_agg<true><<<ab, 256, 0, stream>>>(xwb, dinv, rowp, colsrc, bg2, g2g, g2b,
                                          x1h, x1l, x2h, x2l, waT, a_s, a_d, N);
  // GAT: xwgb = bf16(x2 @ Wgat)
  k_gemm5<128, 64, 128, false, false, 1, 0><<<dim3(gm, 4), 256, 0, stream>>>(
      x2h, x2l, WgatTh, WgatTl, nullptr, xwgb, nullptr, N, 512);
  // softmax-aggregate -> gat planes
  k_gat_agg<<<ab, 256, 0, stream>>>(xwgb, a_s, a_d, rowp, colsrc, bgat, gath, gatl, N);
  // att = relu(gat @ Wao + bao) -> planes
  k_gemm5<512, 64, 128, true, true, 2, 0><<<dim3(gm, 1), 256, 0, stream>>>(
      gath, gatl, WaoTh, WaoTl, bao, atth, attl, N, 128);
  // out = att @ Wout + bout (fp32)
  k_gemm5<128, 128, 64, false, true, 0, 0><<<dim3(gm, 1), 256, 0, stream>>>(
      atth, attl, WoutTh, WoutTl, bout, d_out, nullptr, N, 64);
}

// Round 10
// 544.048 us; speedup vs baseline: 1.8216x; 1.0324x over previous
//
#include <hip/hip_runtime.h>
#include <hip/hip_bf16.h>
#include <cstddef>
#include <cstdint>

#define TPB 256
#define HID 128
#define GATD 512
#define HEADS 4

typedef __attribute__((ext_vector_type(8))) short bf16x8;
typedef __attribute__((ext_vector_type(4))) float f32x4;

__device__ __forceinline__ float lrelu02(float x) { return x > 0.0f ? x : 0.2f * x; }

__device__ __forceinline__ unsigned short f2bf_rn(float f) {
  uint32_t u = __float_as_uint(f);
  u += 0x7fff + ((u >> 16) & 1);
  return (unsigned short)(u >> 16);
}
__device__ __forceinline__ float bf2f(unsigned short h) {
  return __uint_as_float(((uint32_t)h) << 16);
}
__device__ __forceinline__ float bflo(uint32_t u) { return __uint_as_float(u << 16); }
__device__ __forceinline__ float bfhi(uint32_t u) { return __uint_as_float(u & 0xffff0000u); }

// ---------------- utility ----------------
__global__ void k_zero(int* __restrict__ p, int n) {
  int i = blockIdx.x * blockDim.x + threadIdx.x;
  if (i < n) p[i] = 0;
}

// ---------------- CSR build ----------------
__global__ void k_hist(const int* __restrict__ dst, int* __restrict__ cnt, int E) {
  int i = blockIdx.x * blockDim.x + threadIdx.x;
  if (i < E) atomicAdd(&cnt[dst[i]], 1);
}

__global__ __launch_bounds__(256) void k_scan_blk(const int* __restrict__ cnt,
                                                  int* __restrict__ rowp,
                                                  int* __restrict__ bsum,
                                                  float* __restrict__ dinv, int n) {
  __shared__ int wsum[4];
  const int tid = threadIdx.x, lane = tid & 63, wid = tid >> 6;
  const int base = blockIdx.x * 1024 + tid * 4;
  int v[4];
#pragma unroll
  for (int q = 0; q < 4; ++q) {
    int idx = base + q;
    v[q] = (idx < n) ? cnt[idx] : 0;
    if (idx < n) dinv[idx] = rsqrtf((float)(v[q] + 1));  // +1 self loop
  }
  int s = v[0] + v[1] + v[2] + v[3];
  int sc = s;
#pragma unroll
  for (int off = 1; off < 64; off <<= 1) {
    int t = __shfl_up(sc, off);
    if (lane >= off) sc += t;
  }
  if (lane == 63) wsum[wid] = sc;
  __syncthreads();
  int woff = 0;
#pragma unroll
  for (int w = 0; w < 4; ++w)
    if (w < wid) woff += wsum[w];
  int run = woff + sc - s;
#pragma unroll
  for (int q = 0; q < 4; ++q) {
    int idx = base + q;
    if (idx < n) rowp[idx] = run;
    run += v[q];
  }
  if (tid == 255) bsum[blockIdx.x] = woff + sc;
}

__global__ __launch_bounds__(256) void k_scan_top(int* __restrict__ bsum, int nb) {
  __shared__ int sm[256];
  const int tid = threadIdx.x;
  int v = (tid < nb) ? bsum[tid] : 0;
  sm[tid] = v;
  __syncthreads();
  for (int off = 1; off < 256; off <<= 1) {
    int t = (tid >= off) ? sm[tid - off] : 0;
    __syncthreads();
    sm[tid] += t;
    __syncthreads();
  }
  int incl = sm[tid];
  if (tid < nb) bsum[tid] = incl - v;
  if (tid == nb - 1) bsum[nb] = incl;
}

__global__ void k_scan_add(int* __restrict__ rowp, const int* __restrict__ bsum,
                           int n, int nb) {
  int i = blockIdx.x * blockDim.x + threadIdx.x;
  if (i < n) rowp[i] += bsum[i >> 10];
  if (i == 0) rowp[n] = bsum[nb];
}

__global__ void k_fill(const int* __restrict__ src, const int* __restrict__ dst,
                       const int* __restrict__ rowp, int* __restrict__ cur,
                       int* __restrict__ colsrc, int E) {
  int i = blockIdx.x * blockDim.x + threadIdx.x;
  if (i < E) {
    int d = dst[i];
    int pos = rowp[d] + atomicAdd(&cur[d], 1);
    colsrc[pos] = src[i];
  }
}

// ---------------- weight split (transposed hi/lo planes), one launch ----------------
__global__ void k_splitw_all(const float* __restrict__ Win, const float* __restrict__ Wg1,
                             const float* __restrict__ Wg2, const float* __restrict__ Wgat,
                             const float* __restrict__ Wao, const float* __restrict__ Wout,
                             unsigned short* __restrict__ WinTh, unsigned short* __restrict__ WinTl,
                             unsigned short* __restrict__ Wg1Th, unsigned short* __restrict__ Wg1Tl,
                             unsigned short* __restrict__ Wg2Th, unsigned short* __restrict__ Wg2Tl,
                             unsigned short* __restrict__ WgatTh, unsigned short* __restrict__ WgatTl,
                             unsigned short* __restrict__ WaoTh, unsigned short* __restrict__ WaoTl,
                             unsigned short* __restrict__ WoutTh, unsigned short* __restrict__ WoutTl) {
  int t = blockIdx.x * blockDim.x + threadIdx.x;
  const float* W;
  unsigned short *H, *L;
  int K, NC, r;
  if (t < 32768)       { W = Win;  H = WinTh;  L = WinTl;  K = 256; NC = 128; r = t; }
  else if (t < 49152)  { W = Wg1;  H = Wg1Th;  L = Wg1Tl;  K = 128; NC = 128; r = t - 32768; }
  else if (t < 65536)  { W = Wg2;  H = Wg2Th;  L = Wg2Tl;  K = 128; NC = 128; r = t - 49152; }
  else if (t < 131072) { W = Wgat; H = WgatTh; L = WgatTl; K = 128; NC = 512; r = t - 65536; }
  else if (t < 196608) { W = Wao;  H = WaoTh;  L = WaoTl;  K = 512; NC = 128; r = t - 131072; }
  else if (t < 204800) { W = Wout; H = WoutTh; L = WoutTl; K = 128; NC = 64;  r = t - 196608; }
  else return;
  int k = r / NC, n2 = r % NC;
  float v = W[r];
  unsigned short h = f2bf_rn(v);
  H[(size_t)n2 * K + k] = h;
  L[(size_t)n2 * K + k] = f2bf_rn(v - bf2f(h));
}

// ---------------- weight-stationary MFMA GEMM ----------------
// C = act(A @ W + bias); W as (BhT,BlT)[NC,KTOT] transposed hi/lo planes in LDS per chunk.
// AMODE 0: A = (Ah,Al) pre-split planes.  AMODE 1: Ah = fp32 A, split in registers.
// A fragments stream global->register (lane layout == MFMA A-frag layout).
// A*B ~= Ah*Bh + Ah*Bl + Al*Bh.  OUTM: 0=f32, 1=bf16, 2=hi/lo planes.
template <int KTOT, int KC, int NCB, bool RELU, bool BIAS, int OUTM, int AMODE>
__global__ __launch_bounds__(256) void k_gemm5(
    const unsigned short* __restrict__ Ah, const unsigned short* __restrict__ Al,
    const unsigned short* __restrict__ BhT, const unsigned short* __restrict__ BlT,
    const float* __restrict__ bias, void* __restrict__ Cv, void* __restrict__ Cv2,
    int M, int NC) {
  constexpr int NSUB = KC / 32;
  constexpr int NCHUNK = KTOT / KC;
  constexpr int NCF = NCB / 16;
  constexpr int UNITS = NSUB * 2 * 4 * NCB;  // 16B ds_write units per chunk
  __shared__ alignas(16) unsigned short Bs[NSUB][2][4][NCB][8];
  const int tid = threadIdx.x, lane = tid & 63, wid = tid >> 6;
  const int m0 = blockIdx.x * 64;
  const int n0 = blockIdx.y * NCB;
  const int fr = lane & 15, g = lane >> 4;
  const int arow = m0 + wid * 16 + fr;
  const bool aok = arow < M;
  const size_t abase = (size_t)arow * KTOT;

  f32x4 acc[NCF];
#pragma unroll
  for (int cf = 0; cf < NCF; ++cf) acc[cf] = (f32x4){0.f, 0.f, 0.f, 0.f};

  for (int c = 0; c < NCHUNK; ++c) {
    const int c0 = c * KC;
    if (c > 0) __syncthreads();  // previous chunk's reads done
#pragma unroll
    for (int it = 0; it < UNITS / 256; ++it) {
      const int u = tid + it * 256;
      const int n = u % NCB;
      int rest = u / NCB;
      const int kg = rest & 3;
      rest >>= 2;
      const int p = rest & 1;
      const int sub = rest >> 1;
      const unsigned short* sp =
          (p ? BlT : BhT) + (size_t)(n0 + n) * KTOT + c0 + sub * 32 + kg * 8;
      *(uint4*)&Bs[sub][p][kg][n][0] = *(const uint4*)sp;
    }
    __syncthreads();
#pragma unroll
    for (int sub = 0; sub < NSUB; ++sub) {
      const int kb = c0 + sub * 32 + g * 8;
      bf16x8 a_h = {}, a_l = {};
      if (aok) {
        if (AMODE == 0) {
          a_h = *(const bf16x8*)(Ah + abase + kb);
          a_l = *(const bf16x8*)(Al + abase + kb);
        } else {
          const float* Af = (const float*)Ah + abase + kb;
          float4 q0 = *(const float4*)Af;
          float4 q1 = *(const float4*)(Af + 4);
          float av[8] = {q0.x, q0.y, q0.z, q0.w, q1.x, q1.y, q1.z, q1.w};
          union { bf16x8 v; uint32_t u4[4]; } Hu, Lu;
#pragma unroll
          for (int q = 0; q < 4; ++q) {
            unsigned short h0 = f2bf_rn(av[2 * q]);
            unsigned short h1 = f2bf_rn(av[2 * q + 1]);
            unsigned short l0 = f2bf_rn(av[2 * q] - bf2f(h0));
            unsigned short l1 = f2bf_rn(av[2 * q + 1] - bf2f(h1));
            Hu.u4[q] = (uint32_t)h0 | ((uint32_t)h1 << 16);
            Lu.u4[q] = (uint32_t)l0 | ((uint32_t)l1 << 16);
          }
          a_h = Hu.v;
          a_l = Lu.v;
        }
      }
#pragma unroll
      for (int cf = 0; cf < NCF; ++cf) {
        bf16x8 b_h = *(const bf16x8*)&Bs[sub][0][g][cf * 16 + fr][0];
        bf16x8 b_l = *(const bf16x8*)&Bs[sub][1][g][cf * 16 + fr][0];
        acc[cf] = __builtin_amdgcn_mfma_f32_16x16x32_bf16(a_h, b_h, acc[cf], 0, 0, 0);
        acc[cf] = __builtin_amdgcn_mfma_f32_16x16x32_bf16(a_h, b_l, acc[cf], 0, 0, 0);
        acc[cf] = __builtin_amdgcn_mfma_f32_16x16x32_bf16(a_l, b_h, acc[cf], 0, 0, 0);
      }
    }
  }
  // ---- epilogue: D layout col=lane&15, row=(lane>>4)*4+r ----
#pragma unroll
  for (int cf = 0; cf < NCF; ++cf) {
    const int col = n0 + cf * 16 + fr;
    const float bv = BIAS ? bias[col] : 0.f;
#pragma unroll
    for (int r = 0; r < 4; ++r) {
      const int grow = m0 + wid * 16 + g * 4 + r;
      if (grow < M) {
        float v = acc[cf][r] + bv;
        if (RELU) v = fmaxf(v, 0.f);
        const size_t idx = (size_t)grow * NC + col;
        if (OUTM == 0) {
          ((float*)Cv)[idx] = v;
        } else if (OUTM == 1) {
          ((unsigned short*)Cv)[idx] = f2bf_rn(v);
        } else {
          unsigned short h = f2bf_rn(v);
          ((unsigned short*)Cv)[idx] = h;
          ((unsigned short*)Cv2)[idx] = f2bf_rn(v - bf2f(h));
        }
      }
    }
  }
}

// ---------------- GCN aggregate (bf16 gather) + bias + LN + ReLU (+residual, +GAT logits) ----------------
template <bool L2>
__global__ __launch_bounds__(256) void k_gcn_agg(
    const unsigned short* __restrict__ xwb, const float* __restrict__ dinv,
    const int* __restrict__ rowp, const int* __restrict__ colsrc,
    const float* __restrict__ bias, const float* __restrict__ gamma,
    const float* __restrict__ beta,
    const unsigned short* __restrict__ resh, const unsigned short* __restrict__ resl,
    unsigned short* __restrict__ oh, unsigned short* __restrict__ ol,
    const float* __restrict__ waT, float* __restrict__ a_s, float* __restrict__ a_d,
    int n) {
  __shared__ float w[8][HID];
  if (L2) {
    for (int t = threadIdx.x; t < 8 * HID; t += 256) ((float*)w)[t] = waT[t];
    __syncthreads();
  }
  const int lane = threadIdx.x & 63;
  const int i = blockIdx.x * 4 + (threadIdx.x >> 6);
  if (i >= n) return;
  const float di = dinv[i];
  const int c = lane * 2;
  uint32_t v0 = *(const uint32_t*)(xwb + (size_t)i * HID + c);
  float a0 = bflo(v0) * di * di, a1 = bfhi(v0) * di * di;  // self loop
  float b0 = 0.f, b1 = 0.f;
  const int e0 = rowp[i], e1 = rowp[i + 1];
  int j = e0;
  for (; j + 3 < e1; j += 4) {
    int s0 = colsrc[j], s1 = colsrc[j + 1], s2 = colsrc[j + 2], s3 = colsrc[j + 3];
    float w0 = dinv[s0] * di, w1 = dinv[s1] * di, w2 = dinv[s2] * di, w3 = dinv[s3] * di;
    uint32_t u0 = *(const uint32_t*)(xwb + (size_t)s0 * HID + c);
    uint32_t u1 = *(const uint32_t*)(xwb + (size_t)s1 * HID + c);
    uint32_t u2 = *(const uint32_t*)(xwb + (size_t)s2 * HID + c);
    uint32_t u3 = *(const uint32_t*)(xwb + (size_t)s3 * HID + c);
    a0 = fmaf(bflo(u0), w0, a0); a1 = fmaf(bfhi(u0), w0, a1);
    b0 = fmaf(bflo(u1), w1, b0); b1 = fmaf(bfhi(u1), w1, b1);
    a0 = fmaf(bflo(u2), w2, a0); a1 = fmaf(bfhi(u2), w2, a1);
    b0 = fmaf(bflo(u3), w3, b0); b1 = fmaf(bfhi(u3), w3, b1);
  }
  for (; j < e1; ++j) {
    int s0 = colsrc[j];
    float w0 = dinv[s0] * di;
    uint32_t u0 = *(const uint32_t*)(xwb + (size_t)s0 * HID + c);
    a0 = fmaf(bflo(u0), w0, a0);
    a1 = fmaf(bfhi(u0), w0, a1);
  }
  a0 += b0;
  a1 += b1;
  a0 += bias[c];
  a1 += bias[c + 1];
  float s1 = a0 + a1, s2 = a0 * a0 + a1 * a1;
#pragma unroll
  for (int m = 32; m >= 1; m >>= 1) {
    s1 += __shfl_xor(s1, m);
    s2 += __shfl_xor(s2, m);
  }
  float mu = s1 * (1.0f / HID);
  float var = s2 * (1.0f / HID) - mu * mu;
  float rstd = rsqrtf(var + 1e-5f);
  float y0 = fmaxf((a0 - mu) * rstd * gamma[c] + beta[c], 0.0f);
  float y1 = fmaxf((a1 - mu) * rstd * gamma[c + 1] + beta[c + 1], 0.0f);
  if (L2) {
    uint32_t rh = *(const uint32_t*)(resh + (size_t)i * HID + c);
    uint32_t rl = *(const uint32_t*)(resl + (size_t)i * HID + c);
    y0 += bflo(rh) + bflo(rl);
    y1 += bfhi(rh) + bfhi(rl);
  }
  unsigned short ph0 = f2bf_rn(y0), ph1 = f2bf_rn(y1);
  uint32_t hw = (uint32_t)ph0 | ((uint32_t)ph1 << 16);
  uint32_t lw = (uint32_t)f2bf_rn(y0 - bf2f(ph0)) |
                ((uint32_t)f2bf_rn(y1 - bf2f(ph1)) << 16);
  *(uint32_t*)(oh + (size_t)i * HID + c) = hw;
  *(uint32_t*)(ol + (size_t)i * HID + c) = lw;
  if (L2) {
    float p[8];
#pragma unroll
    for (int h = 0; h < 8; ++h) p[h] = y0 * w[h][c] + y1 * w[h][c + 1];
#pragma unroll
    for (int m = 32; m >= 1; m >>= 1) {
#pragma unroll
      for (int h = 0; h < 8; ++h) p[h] += __shfl_xor(p[h], m);
    }
    if (lane == 0) {
      a_s[i * 4 + 0] = p[0]; a_s[i * 4 + 1] = p[1];
      a_s[i * 4 + 2] = p[2]; a_s[i * 4 + 3] = p[3];
      a_d[i * 4 + 0] = p[4]; a_d[i * 4 + 1] = p[5];
      a_d[i * 4 + 2] = p[6]; a_d[i * 4 + 3] = p[7];
    }
  }
}

// ---------------- fold Wgat into attention vectors ----------------
__global__ __launch_bounds__(256) void k_wprep(const float* __restrict__ Wgat,
                                               const float* __restrict__ att_src,
                                               const float* __restrict__ att_dst,
                                               float* __restrict__ waT) {
  int t = blockIdx.x * blockDim.x + threadIdx.x;  // 0..1023
  if (t >= 1024) return;
  int p = t >> 7, k = t & 127;
  int h = p & 3;
  const float* av = (p < 4 ? att_src : att_dst) + h * HID;
  const float* wrow = Wgat + (size_t)k * GATD + h * HID;
  float s = 0.f;
#pragma unroll 4
  for (int c = 0; c < HID; ++c) s = fmaf(wrow[c], av[c], s);
  waT[t] = s;
}

// ---------------- GAT softmax-aggregate (wave/node), bf16 table, plane output ----------------
__global__ __launch_bounds__(256) void k_gat_agg(const unsigned short* __restrict__ xwgb,
                                                 const float* __restrict__ a_s,
                                                 const float* __restrict__ a_d,
                                                 const int* __restrict__ rowp,
                                                 const int* __restrict__ colsrc,
                                                 const float* __restrict__ bias,
                                                 unsigned short* __restrict__ gath,
                                                 unsigned short* __restrict__ gatl,
                                                 int n) {
  const int lane = threadIdx.x & 63;
  const int i = blockIdx.x * 4 + (threadIdx.x >> 6);
  if (i >= n) return;
  const float4 adv = *(const float4*)(a_d + i * 4);
  const float4 asv = *(const float4*)(a_s + i * 4);
  float es0 = lrelu02(asv.x + adv.x);
  float es1 = lrelu02(asv.y + adv.y);
  float es2 = lrelu02(asv.z + adv.z);
  float es3 = lrelu02(asv.w + adv.w);
  const int e0 = rowp[i], e1 = rowp[i + 1];
  // pass 1: max
  float m0 = es0, m1 = es1, m2 = es2, m3 = es3;
  for (int j = e0 + lane; j < e1; j += 64) {
    int s = colsrc[j];
    const float4 av = *(const float4*)(a_s + s * 4);
    m0 = fmaxf(m0, lrelu02(av.x + adv.x));
    m1 = fmaxf(m1, lrelu02(av.y + adv.y));
    m2 = fmaxf(m2, lrelu02(av.z + adv.z));
    m3 = fmaxf(m3, lrelu02(av.w + adv.w));
  }
#pragma unroll
  for (int m = 32; m >= 1; m >>= 1) {
    m0 = fmaxf(m0, __shfl_xor(m0, m));
    m1 = fmaxf(m1, __shfl_xor(m1, m));
    m2 = fmaxf(m2, __shfl_xor(m2, m));
    m3 = fmaxf(m3, __shfl_xor(m3, m));
  }
  // pass 2: denom
  float d0 = 0.f, d1 = 0.f, d2 = 0.f, d3 = 0.f;
  for (int j = e0 + lane; j < e1; j += 64) {
    int s = colsrc[j];
    const float4 av = *(const float4*)(a_s + s * 4);
    d0 += __expf(lrelu02(av.x + adv.x) - m0);
    d1 += __expf(lrelu02(av.y + adv.y) - m1);
    d2 += __expf(lrelu02(av.z + adv.z) - m2);
    d3 += __expf(lrelu02(av.w + adv.w) - m3);
  }
#pragma unroll
  for (int m = 32; m >= 1; m >>= 1) {
    d0 += __shfl_xor(d0, m);
    d1 += __shfl_xor(d1, m);
    d2 += __shfl_xor(d2, m);
    d3 += __shfl_xor(d3, m);
  }
  d0 += __expf(es0 - m0);
  d1 += __expf(es1 - m1);
  d2 += __expf(es2 - m2);
  d3 += __expf(es3 - m3);
  const float inv0 = 1.0f / d0, inv1 = 1.0f / d1, inv2 = 1.0f / d2, inv3 = 1.0f / d3;
  const int col = lane * 8;
  const int h = lane >> 4;
  const float mh = (h < 2) ? (h == 0 ? m0 : m1) : (h == 2 ? m2 : m3);
  const float invh = (h < 2) ? (h == 0 ? inv0 : inv1) : (h == 2 ? inv2 : inv3);
  const float adh = (h < 2) ? (h == 0 ? adv.x : adv.y) : (h == 2 ? adv.z : adv.w);
  const float esh = (h < 2) ? (h == 0 ? es0 : es1) : (h == 2 ? es2 : es3);
  const float aself = __expf(esh - mh) * invh;
  // pass 3: alpha-weighted bf16 message accumulation, 4-edge unroll, dual chains
  uint4 u = *(const uint4*)(xwgb + (size_t)i * GATD + col);
  float4 accA0 = make_float4(bflo(u.x) * aself, bfhi(u.x) * aself,
                             bflo(u.y) * aself, bfhi(u.y) * aself);
  float4 accA1 = make_float4(bflo(u.z) * aself, bfhi(u.z) * aself,
                             bflo(u.w) * aself, bfhi(u.w) * aself);
  float4 accB0 = make_float4(0.f, 0.f, 0.f, 0.f);
  float4 accB1 = make_float4(0.f, 0.f, 0.f, 0.f);
  int j = e0;
  for (; j + 3 < e1; j += 4) {
    int s0 = colsrc[j], s1 = colsrc[j + 1], s2 = colsrc[j + 2], s3 = colsrc[j + 3];
    float al0 = __expf(lrelu02(a_s[s0 * 4 + h] + adh) - mh) * invh;
    float al1 = __expf(lrelu02(a_s[s1 * 4 + h] + adh) - mh) * invh;
    float al2 = __expf(lrelu02(a_s[s2 * 4 + h] + adh) - mh) * invh;
    float al3 = __expf(lrelu02(a_s[s3 * 4 + h] + adh) - mh) * invh;
    uint4 w0 = *(const uint4*)(xwgb + (size_t)s0 * GATD + col);
    uint4 w1 = *(const uint4*)(xwgb + (size_t)s1 * GATD + col);
    uint4 w2 = *(const uint4*)(xwgb + (size_t)s2 * GATD + col);
    uint4 w3 = *(const uint4*)(xwgb + (size_t)s3 * GATD + col);
    accA0.x = fmaf(bflo(w0.x), al0, accA0.x); accA0.y = fmaf(bfhi(w0.x), al0, accA0.y);
    accA0.z = fmaf(bflo(w0.y), al0, accA0.z); accA0.w = fmaf(bfhi(w0.y), al0, accA0.w);
    accA1.x = fmaf(bflo(w0.z), al0, accA1.x); accA1.y = fmaf(bfhi(w0.z), al0, accA1.y);
    accA1.z = fmaf(bflo(w0.w), al0, accA1.z); accA1.w = fmaf(bfhi(w0.w), al0, accA1.w);
    accB0.x = fmaf(bflo(w1.x), al1, accB0.x); accB0.y = fmaf(bfhi(w1.x), al1, accB0.y);
    accB0.z = fmaf(bflo(w1.y), al1, accB0.z); accB0.w = fmaf(bfhi(w1.y), al1, accB0.w);
    accB1.x = fmaf(bflo(w1.z), al1, accB1.x); accB1.y = fmaf(bfhi(w1.z), al1, accB1.y);
    accB1.z = fmaf(bflo(w1.w), al1, accB1.z); accB1.w = fmaf(bfhi(w1.w), al1, accB1.w);
    accA0.x = fmaf(bflo(w2.x), al2, accA0.x); accA0.y = fmaf(bfhi(w2.x), al2, accA0.y);
    accA0.z = fmaf(bflo(w2.y), al2, accA0.z); accA0.w = fmaf(bfhi(w2.y), al2, accA0.w);
    accA1.x = fmaf(bflo(w2.z), al2, accA1.x); accA1.y = fmaf(bfhi(w2.z), al2, accA1.y);
    accA1.z = fmaf(bflo(w2.w), al2, accA1.z); accA1.w = fmaf(bfhi(w2.w), al2, accA1.w);
    accB0.x = fmaf(bflo(w3.x), al3, accB0.x); accB0.y = fmaf(bfhi(w3.x), al3, accB0.y);
    accB0.z = fmaf(bflo(w3.y), al3, accB0.z); accB0.w = fmaf(bfhi(w3.y), al3, accB0.w);
    accB1.x = fmaf(bflo(w3.z), al3, accB1.x); accB1.y = fmaf(bfhi(w3.z), al3, accB1.y);
    accB1.z = fmaf(bflo(w3.w), al3, accB1.z); accB1.w = fmaf(bfhi(w3.w), al3, accB1.w);
  }
  for (; j < e1; ++j) {
    int s0 = colsrc[j];
    float al0 = __expf(lrelu02(a_s[s0 * 4 + h] + adh) - mh) * invh;
    uint4 w0 = *(const uint4*)(xwgb + (size_t)s0 * GATD + col);
    accA0.x = fmaf(bflo(w0.x), al0, accA0.x); accA0.y = fmaf(bfhi(w0.x), al0, accA0.y);
    accA0.z = fmaf(bflo(w0.y), al0, accA0.z); accA0.w = fmaf(bfhi(w0.y), al0, accA0.w);
    accA1.x = fmaf(bflo(w0.z), al0, accA1.x); accA1.y = fmaf(bfhi(w0.z), al0, accA1.y);
    accA1.z = fmaf(bflo(w0.w), al0, accA1.z); accA1.w = fmaf(bfhi(w0.w), al0, accA1.w);
  }
  accA0.x += accB0.x; accA0.y += accB0.y; accA0.z += accB0.z; accA0.w += accB0.w;
  accA1.x += accB1.x; accA1.y += accB1.y; accA1.z += accB1.z; accA1.w += accB1.w;
  const float4* bp = (const float4*)(bias + col);
  float4 b0 = bp[0], b1 = bp[1];
  float vv[8] = {accA0.x + b0.x, accA0.y + b0.y, accA0.z + b0.z, accA0.w + b0.w,
                 accA1.x + b1.x, accA1.y + b1.y, accA1.z + b1.z, accA1.w + b1.w};
  uint32_t hv[4], lv[4];
#pragma unroll
  for (int q = 0; q < 4; ++q) {
    unsigned short ha = f2bf_rn(vv[2 * q]), hb = f2bf_rn(vv[2 * q + 1]);
    unsigned short la = f2bf_rn(vv[2 * q] - bf2f(ha));
    unsigned short lb = f2bf_rn(vv[2 * q + 1] - bf2f(hb));
    hv[q] = (uint32_t)ha | ((uint32_t)hb << 16);
    lv[q] = (uint32_t)la | ((uint32_t)lb << 16);
  }
  *(uint4*)(gath + (size_t)i * GATD + col) = make_uint4(hv[0], hv[1], hv[2], hv[3]);
  *(uint4*)(gatl + (size_t)i * GATD + col) = make_uint4(lv[0], lv[1], lv[2], lv[3]);
}

extern "C" void kernel_launch(void* const* d_in, const int* in_sizes, int n_in,
                              void* d_out, int out_size, void* d_ws, size_t ws_size,
                              hipStream_t stream) {
  const float* x = (const float*)d_in[0];
  const int* ei = (const int*)d_in[1];
  const float* Win = (const float*)d_in[2];
  const float* bin = (const float*)d_in[3];
  const float* Wg1 = (const float*)d_in[4];
  const float* bg1 = (const float*)d_in[5];
  const float* g1g = (const float*)d_in[6];
  const float* g1b = (const float*)d_in[7];
  const float* Wg2 = (const float*)d_in[8];
  const float* bg2 = (const float*)d_in[9];
  const float* g2g = (const float*)d_in[10];
  const float* g2b = (const float*)d_in[11];
  const float* Wgat = (const float*)d_in[12];
  const float* att_s = (const float*)d_in[13];
  const float* att_d = (const float*)d_in[14];
  const float* bgat = (const float*)d_in[15];
  const float* Wao = (const float*)d_in[16];
  const float* bao = (const float*)d_in[17];
  const float* Wout = (const float*)d_in[18];
  const float* bout = (const float*)d_in[19];

  const int N = in_sizes[0] / 256;
  const int E = in_sizes[1] / 2;
  const int* src = ei;
  const int* dst = ei + E;

  // ---- workspace layout (bytes), ~195 MB ----
  char* base = (char*)d_ws;
  size_t off = 0;
  unsigned short* gath = (unsigned short*)(base + off); off += (size_t)N * GATD * 2;
  unsigned short* h0h = (unsigned short*)(base + off); off += (size_t)N * HID * 2;
  unsigned short* h0l = (unsigned short*)(base + off); off += (size_t)N * HID * 2;
  unsigned short* x1h = (unsigned short*)(base + off); off += (size_t)N * HID * 2;
  unsigned short* x1l = (unsigned short*)(base + off); off += (size_t)N * HID * 2;
  unsigned short* gatl = h0h;  // h0|x1 planes (51.2MB contig) dead by GAT agg
  unsigned short* xwb = (unsigned short*)(base + off); off += (size_t)N * HID * 2;
  unsigned short* x2h = (unsigned short*)(base + off); off += (size_t)N * HID * 2;
  unsigned short* x2l = (unsigned short*)(base + off); off += (size_t)N * HID * 2;
  unsigned short* atth = x2h;  // reuse after Wgat GEMM
  unsigned short* attl = x2l;
  unsigned short* xwgb = (unsigned short*)(base + off); off += (size_t)N * GATD * 2;
  float* dinv = (float*)(base + off);                  off += (size_t)N * 4;
  float* a_s = (float*)(base + off);                   off += (size_t)N * 16;
  float* a_d = (float*)(base + off);                   off += (size_t)N * 16;
  float* waT = (float*)(base + off);                   off += 4096;
  unsigned short *WinTh, *WinTl, *Wg1Th, *Wg1Tl, *Wg2Th, *Wg2Tl;
  unsigned short *WgatTh, *WgatTl, *WaoTh, *WaoTl, *WoutTh, *WoutTl;
  WinTh = (unsigned short*)(base + off);  off += 256 * 128 * 2;
  WinTl = (unsigned short*)(base + off);  off += 256 * 128 * 2;
  Wg1Th = (unsigned short*)(base + off);  off += 128 * 128 * 2;
  Wg1Tl = (unsigned short*)(base + off);  off += 128 * 128 * 2;
  Wg2Th = (unsigned short*)(base + off);  off += 128 * 128 * 2;
  Wg2Tl = (unsigned short*)(base + off);  off += 128 * 128 * 2;
  WgatTh = (unsigned short*)(base + off); off += 128 * 512 * 2;
  WgatTl = (unsigned short*)(base + off); off += 128 * 512 * 2;
  WaoTh = (unsigned short*)(base + off);  off += 512 * 128 * 2;
  WaoTl = (unsigned short*)(base + off);  off += 512 * 128 * 2;
  WoutTh = (unsigned short*)(base + off); off += 128 * 64 * 2;
  WoutTl = (unsigned short*)(base + off); off += 128 * 64 * 2;
  int* rowp = (int*)(base + off);   off += (size_t)(N + 1) * 4;
  int* colsrc = (int*)(base + off); off += (size_t)E * 4;
  const int nb2 = (N + 1023) / 1024;
  int* bsum = (int*)(base + off);   off += (size_t)(nb2 + 2) * 4;
  int* cnt = (int*)xwgb;  // alias: dead before xwgb is written
  int* cur = cnt + N;

  const int eb = (E + TPB - 1) / TPB;
  const int zb = (2 * N + TPB - 1) / TPB;
  const int ab = (N + 3) / 4;
  const int gm = (N + 63) / 64;

  // CSR + prep
  k_zero<<<zb, TPB, 0, stream>>>(cnt, 2 * N);
  k_hist<<<eb, TPB, 0, stream>>>(dst, cnt, E);
  k_scan_blk<<<nb2, 256, 0, stream>>>(cnt, rowp, bsum, dinv, N);
  k_scan_top<<<1, 256, 0, stream>>>(bsum, nb2);
  k_scan_add<<<(N + 255) / 256, 256, 0, stream>>>(rowp, bsum, N, nb2);
  k_fill<<<eb, TPB, 0, stream>>>(src, dst, rowp, cur, colsrc, E);
  k_wprep<<<4, 256, 0, stream>>>(Wgat, att_s, att_d, waT);
  k_splitw_all<<<(204800 + 255) / 256, 256, 0, stream>>>(
      Win, Wg1, Wg2, Wgat, Wao, Wout, WinTh, WinTl, Wg1Th, Wg1Tl, Wg2Th, Wg2Tl,
      WgatTh, WgatTl, WaoTh, WaoTl, WoutTh, WoutTl);

  // h0 = relu(x @ Win + bin) -> planes    [fp32 A split in regs]
  k_gemm5<256, 64, 128, true, true, 2, 1><<<dim3(gm, 1), 256, 0, stream>>>(
      (const unsigned short*)x, nullptr, WinTh, WinTl, bin, h0h, h0l, N, 128);
  // GCN layer 1: xwb = bf16(h0 @ Wg1)
  k_gemm5<128, 64, 128, false, false, 1, 0><<<dim3(gm, 1), 256, 0, stream>>>(
      h0h, h0l, Wg1Th, Wg1Tl, nullptr, xwb, nullptr, N, 128);
  k_gcn_agg<false><<<ab, 256, 0, stream>>>(xwb, dinv, rowp, colsrc, bg1, g1g, g1b,
                                           nullptr, nullptr, x1h, x1l,
                                           nullptr, nullptr, nullptr, N);
  // GCN layer 2 (+residual, +fused GAT logits)
  k_gemm5<128, 64, 128, false, false, 1, 0><<<dim3(gm, 1), 256, 0, stream>>>(
      x1h, x1l, Wg2Th, Wg2Tl, nullptr, xwb, nullptr, N, 128);
  k_gcn_agg<true><<<ab, 256, 0, stream>>>(xwb, dinv, rowp, colsrc, bg2, g2g, g2b,
                                          x1h, x1l, x2h, x2l, waT, a_s, a_d, N);
  // GAT: xwgb = bf16(x2 @ Wgat)   [NCB=256, KC=32, y=2 -> A read 2x not 4x]
  k_gemm5<128, 32, 256, false, false, 1, 0><<<dim3(gm, 2), 256, 0, stream>>>(
      x2h, x2l, WgatTh, WgatTl, nullptr, xwgb, nullptr, N, 512);
  // softmax-aggregate -> gat planes
  k_gat_agg<<<ab, 256, 0, stream>>>(xwgb, a_s, a_d, rowp, colsrc, bgat, gath, gatl, N);
  // att = relu(gat @ Wao + bao) -> planes
  k_gemm5<512, 64, 128, true, true, 2, 0><<<dim3(gm, 1), 256, 0, stream>>>(
      gath, gatl, WaoTh, WaoTl, bao, atth, attl, N, 128);
  // out = att @ Wout + bout (fp32)
  k_gemm5<128, 128, 64, false, true, 0, 0><<<dim3(gm, 1), 256, 0, stream>>>(
      atth, attl, WoutTh, WoutTl, bout, d_out, nullptr, N, 64);
}

// Round 11
// 495.793 us; speedup vs baseline: 1.9989x; 1.0973x over previous
//
#include <hip/hip_runtime.h>
#include <hip/hip_bf16.h>
#include <cstddef>
#include <cstdint>

#define TPB 256
#define HID 128
#define GATD 512
#define HEADS 4

typedef __attribute__((ext_vector_type(8))) short bf16x8;
typedef __attribute__((ext_vector_type(4))) float f32x4;

__device__ __forceinline__ float lrelu02(float x) { return x > 0.0f ? x : 0.2f * x; }

__device__ __forceinline__ unsigned short f2bf_rn(float f) {
  uint32_t u = __float_as_uint(f);
  u += 0x7fff + ((u >> 16) & 1);
  return (unsigned short)(u >> 16);
}
__device__ __forceinline__ float bf2f(unsigned short h) {
  return __uint_as_float(((uint32_t)h) << 16);
}
__device__ __forceinline__ float bflo(uint32_t u) { return __uint_as_float(u << 16); }
__device__ __forceinline__ float bfhi(uint32_t u) { return __uint_as_float(u & 0xffff0000u); }

// ---------------- utility ----------------
__global__ void k_zero(int* __restrict__ p, int n) {
  int i = blockIdx.x * blockDim.x + threadIdx.x;
  if (i < n) p[i] = 0;
}

// ---------------- CSR build ----------------
__global__ void k_hist(const int* __restrict__ dst, int* __restrict__ cnt, int E) {
  int i = blockIdx.x * blockDim.x + threadIdx.x;
  if (i < E) atomicAdd(&cnt[dst[i]], 1);
}

__global__ __launch_bounds__(256) void k_scan_blk(const int* __restrict__ cnt,
                                                  int* __restrict__ rowp,
                                                  int* __restrict__ bsum,
                                                  float* __restrict__ dinv, int n) {
  __shared__ int wsum[4];
  const int tid = threadIdx.x, lane = tid & 63, wid = tid >> 6;
  const int base = blockIdx.x * 1024 + tid * 4;
  int v[4];
#pragma unroll
  for (int q = 0; q < 4; ++q) {
    int idx = base + q;
    v[q] = (idx < n) ? cnt[idx] : 0;
    if (idx < n) dinv[idx] = rsqrtf((float)(v[q] + 1));  // +1 self loop
  }
  int s = v[0] + v[1] + v[2] + v[3];
  int sc = s;
#pragma unroll
  for (int off = 1; off < 64; off <<= 1) {
    int t = __shfl_up(sc, off);
    if (lane >= off) sc += t;
  }
  if (lane == 63) wsum[wid] = sc;
  __syncthreads();
  int woff = 0;
#pragma unroll
  for (int w = 0; w < 4; ++w)
    if (w < wid) woff += wsum[w];
  int run = woff + sc - s;
#pragma unroll
  for (int q = 0; q < 4; ++q) {
    int idx = base + q;
    if (idx < n) rowp[idx] = run;
    run += v[q];
  }
  if (tid == 255) bsum[blockIdx.x] = woff + sc;
}

__global__ __launch_bounds__(256) void k_scan_top(int* __restrict__ bsum, int nb) {
  __shared__ int sm[256];
  const int tid = threadIdx.x;
  int v = (tid < nb) ? bsum[tid] : 0;
  sm[tid] = v;
  __syncthreads();
  for (int off = 1; off < 256; off <<= 1) {
    int t = (tid >= off) ? sm[tid - off] : 0;
    __syncthreads();
    sm[tid] += t;
    __syncthreads();
  }
  int incl = sm[tid];
  if (tid < nb) bsum[tid] = incl - v;
  if (tid == nb - 1) bsum[nb] = incl;
}

__global__ void k_scan_add(int* __restrict__ rowp, const int* __restrict__ bsum,
                           int n, int nb) {
  int i = blockIdx.x * blockDim.x + threadIdx.x;
  if (i < n) rowp[i] += bsum[i >> 10];
  if (i == 0) rowp[n] = bsum[nb];
}

__global__ void k_fill(const int* __restrict__ src, const int* __restrict__ dst,
                       const int* __restrict__ rowp, int* __restrict__ cur,
                       int* __restrict__ colsrc, int E) {
  int i = blockIdx.x * blockDim.x + threadIdx.x;
  if (i < E) {
    int d = dst[i];
    int pos = rowp[d] + atomicAdd(&cur[d], 1);
    colsrc[pos] = src[i];
  }
}

// ---------------- weight split (transposed hi/lo planes): Win, Wg1, Wg2, Wout ----------------
__global__ void k_splitw_all(const float* __restrict__ Win, const float* __restrict__ Wg1,
                             const float* __restrict__ Wg2, const float* __restrict__ Wout,
                             unsigned short* __restrict__ WinTh, unsigned short* __restrict__ WinTl,
                             unsigned short* __restrict__ Wg1Th, unsigned short* __restrict__ Wg1Tl,
                             unsigned short* __restrict__ Wg2Th, unsigned short* __restrict__ Wg2Tl,
                             unsigned short* __restrict__ WoutTh, unsigned short* __restrict__ WoutTl) {
  int t = blockIdx.x * blockDim.x + threadIdx.x;
  const float* W;
  unsigned short *H, *L;
  int K, NC, r;
  if (t < 32768)      { W = Win;  H = WinTh;  L = WinTl;  K = 256; NC = 128; r = t; }
  else if (t < 49152) { W = Wg1;  H = Wg1Th;  L = Wg1Tl;  K = 128; NC = 128; r = t - 32768; }
  else if (t < 65536) { W = Wg2;  H = Wg2Th;  L = Wg2Tl;  K = 128; NC = 128; r = t - 49152; }
  else if (t < 73728) { W = Wout; H = WoutTh; L = WoutTl; K = 128; NC = 64;  r = t - 65536; }
  else return;
  int k = r / NC, n2 = r % NC;
  float v = W[r];
  unsigned short h = f2bf_rn(v);
  H[(size_t)n2 * K + k] = h;
  L[(size_t)n2 * K + k] = f2bf_rn(v - bf2f(h));
}

// ---------------- fold Wao into Wgat per head: VT[j][k] planes, j = c*4+h interleaved ----------------
__global__ __launch_bounds__(256) void k_vprep(const float* __restrict__ Wgat,
                                               const float* __restrict__ Wao,
                                               unsigned short* __restrict__ VTh,
                                               unsigned short* __restrict__ VTl) {
  int t = blockIdx.x * blockDim.x + threadIdx.x;  // 0..65535
  if (t >= 512 * 128) return;
  int j = t >> 7, k = t & 127;
  int c = j >> 2, h = j & 3;
  const float* wg = Wgat + (size_t)k * GATD + h * HID;      // Wgat[k, h*128 + d]
  const float* wa = Wao + (size_t)(h * HID) * HID + c;      // Wao[h*128 + d, c], stride 128
  float s = 0.f;
#pragma unroll 4
  for (int d = 0; d < HID; ++d) s = fmaf(wg[d], wa[(size_t)d * HID], s);
  unsigned short hi = f2bf_rn(s);
  VTh[(size_t)j * HID + k] = hi;
  VTl[(size_t)j * HID + k] = f2bf_rn(s - bf2f(hi));
}

// cb[c] = bao[c] + sum_d bgat[d] * Wao[d][c]
__global__ void k_cbias(const float* __restrict__ bgat, const float* __restrict__ Wao,
                        const float* __restrict__ bao, float* __restrict__ cb) {
  int c = threadIdx.x;
  if (c >= HID) return;
  float s = bao[c];
  for (int d = 0; d < GATD; ++d) s = fmaf(bgat[d], Wao[(size_t)d * HID + c], s);
  cb[c] = s;
}

// ---------------- weight-stationary MFMA GEMM ----------------
// C = act(A @ W + bias); W as (BhT,BlT)[NC,KTOT] transposed hi/lo planes in LDS per chunk.
// AMODE 0: A = (Ah,Al) pre-split planes.  AMODE 1: Ah = fp32 A, split in registers.
// A*B ~= Ah*Bh + Ah*Bl + Al*Bh.  OUTM: 0=f32, 1=bf16, 2=hi/lo planes.
template <int KTOT, int KC, int NCB, bool RELU, bool BIAS, int OUTM, int AMODE>
__global__ __launch_bounds__(256) void k_gemm5(
    const unsigned short* __restrict__ Ah, const unsigned short* __restrict__ Al,
    const unsigned short* __restrict__ BhT, const unsigned short* __restrict__ BlT,
    const float* __restrict__ bias, void* __restrict__ Cv, void* __restrict__ Cv2,
    int M, int NC) {
  constexpr int NSUB = KC / 32;
  constexpr int NCHUNK = KTOT / KC;
  constexpr int NCF = NCB / 16;
  constexpr int UNITS = NSUB * 2 * 4 * NCB;
  __shared__ alignas(16) unsigned short Bs[NSUB][2][4][NCB][8];
  const int tid = threadIdx.x, lane = tid & 63, wid = tid >> 6;
  const int m0 = blockIdx.x * 64;
  const int n0 = blockIdx.y * NCB;
  const int fr = lane & 15, g = lane >> 4;
  const int arow = m0 + wid * 16 + fr;
  const bool aok = arow < M;
  const size_t abase = (size_t)arow * KTOT;

  f32x4 acc[NCF];
#pragma unroll
  for (int cf = 0; cf < NCF; ++cf) acc[cf] = (f32x4){0.f, 0.f, 0.f, 0.f};

  for (int c = 0; c < NCHUNK; ++c) {
    const int c0 = c * KC;
    if (c > 0) __syncthreads();
#pragma unroll
    for (int it = 0; it < UNITS / 256; ++it) {
      const int u = tid + it * 256;
      const int n = u % NCB;
      int rest = u / NCB;
      const int kg = rest & 3;
      rest >>= 2;
      const int p = rest & 1;
      const int sub = rest >> 1;
      const unsigned short* sp =
          (p ? BlT : BhT) + (size_t)(n0 + n) * KTOT + c0 + sub * 32 + kg * 8;
      *(uint4*)&Bs[sub][p][kg][n][0] = *(const uint4*)sp;
    }
    __syncthreads();
#pragma unroll
    for (int sub = 0; sub < NSUB; ++sub) {
      const int kb = c0 + sub * 32 + g * 8;
      bf16x8 a_h = {}, a_l = {};
      if (aok) {
        if (AMODE == 0) {
          a_h = *(const bf16x8*)(Ah + abase + kb);
          a_l = *(const bf16x8*)(Al + abase + kb);
        } else {
          const float* Af = (const float*)Ah + abase + kb;
          float4 q0 = *(const float4*)Af;
          float4 q1 = *(const float4*)(Af + 4);
          float av[8] = {q0.x, q0.y, q0.z, q0.w, q1.x, q1.y, q1.z, q1.w};
          union { bf16x8 v; uint32_t u4[4]; } Hu, Lu;
#pragma unroll
          for (int q = 0; q < 4; ++q) {
            unsigned short h0 = f2bf_rn(av[2 * q]);
            unsigned short h1 = f2bf_rn(av[2 * q + 1]);
            unsigned short l0 = f2bf_rn(av[2 * q] - bf2f(h0));
            unsigned short l1 = f2bf_rn(av[2 * q + 1] - bf2f(h1));
            Hu.u4[q] = (uint32_t)h0 | ((uint32_t)h1 << 16);
            Lu.u4[q] = (uint32_t)l0 | ((uint32_t)l1 << 16);
          }
          a_h = Hu.v;
          a_l = Lu.v;
        }
      }
#pragma unroll
      for (int cf = 0; cf < NCF; ++cf) {
        bf16x8 b_h = *(const bf16x8*)&Bs[sub][0][g][cf * 16 + fr][0];
        bf16x8 b_l = *(const bf16x8*)&Bs[sub][1][g][cf * 16 + fr][0];
        acc[cf] = __builtin_amdgcn_mfma_f32_16x16x32_bf16(a_h, b_h, acc[cf], 0, 0, 0);
        acc[cf] = __builtin_amdgcn_mfma_f32_16x16x32_bf16(a_h, b_l, acc[cf], 0, 0, 0);
        acc[cf] = __builtin_amdgcn_mfma_f32_16x16x32_bf16(a_l, b_h, acc[cf], 0, 0, 0);
      }
    }
  }
#pragma unroll
  for (int cf = 0; cf < NCF; ++cf) {
    const int col = n0 + cf * 16 + fr;
    const float bv = BIAS ? bias[col] : 0.f;
#pragma unroll
    for (int r = 0; r < 4; ++r) {
      const int grow = m0 + wid * 16 + g * 4 + r;
      if (grow < M) {
        float v = acc[cf][r] + bv;
        if (RELU) v = fmaxf(v, 0.f);
        const size_t idx = (size_t)grow * NC + col;
        if (OUTM == 0) {
          ((float*)Cv)[idx] = v;
        } else if (OUTM == 1) {
          ((unsigned short*)Cv)[idx] = f2bf_rn(v);
        } else {
          unsigned short h = f2bf_rn(v);
          ((unsigned short*)Cv)[idx] = h;
          ((unsigned short*)Cv2)[idx] = f2bf_rn(v - bf2f(h));
        }
      }
    }
  }
}

// ---------------- GCN aggregate (bf16 gather) + bias + LN + ReLU (+residual, +GAT logits) ----------------
template <bool L2>
__global__ __launch_bounds__(256) void k_gcn_agg(
    const unsigned short* __restrict__ xwb, const float* __restrict__ dinv,
    const int* __restrict__ rowp, const int* __restrict__ colsrc,
    const float* __restrict__ bias, const float* __restrict__ gamma,
    const float* __restrict__ beta,
    const unsigned short* __restrict__ resh, const unsigned short* __restrict__ resl,
    unsigned short* __restrict__ oh, unsigned short* __restrict__ ol,
    const float* __restrict__ waT, float* __restrict__ a_s, float* __restrict__ a_d,
    int n) {
  __shared__ float w[8][HID];
  if (L2) {
    for (int t = threadIdx.x; t < 8 * HID; t += 256) ((float*)w)[t] = waT[t];
    __syncthreads();
  }
  const int lane = threadIdx.x & 63;
  const int i = blockIdx.x * 4 + (threadIdx.x >> 6);
  if (i >= n) return;
  const float di = dinv[i];
  const int c = lane * 2;
  uint32_t v0 = *(const uint32_t*)(xwb + (size_t)i * HID + c);
  float a0 = bflo(v0) * di * di, a1 = bfhi(v0) * di * di;  // self loop
  float b0 = 0.f, b1 = 0.f;
  const int e0 = rowp[i], e1 = rowp[i + 1];
  int j = e0;
  for (; j + 3 < e1; j += 4) {
    int s0 = colsrc[j], s1 = colsrc[j + 1], s2 = colsrc[j + 2], s3 = colsrc[j + 3];
    float w0 = dinv[s0] * di, w1 = dinv[s1] * di, w2 = dinv[s2] * di, w3 = dinv[s3] * di;
    uint32_t u0 = *(const uint32_t*)(xwb + (size_t)s0 * HID + c);
    uint32_t u1 = *(const uint32_t*)(xwb + (size_t)s1 * HID + c);
    uint32_t u2 = *(const uint32_t*)(xwb + (size_t)s2 * HID + c);
    uint32_t u3 = *(const uint32_t*)(xwb + (size_t)s3 * HID + c);
    a0 = fmaf(bflo(u0), w0, a0); a1 = fmaf(bfhi(u0), w0, a1);
    b0 = fmaf(bflo(u1), w1, b0); b1 = fmaf(bfhi(u1), w1, b1);
    a0 = fmaf(bflo(u2), w2, a0); a1 = fmaf(bfhi(u2), w2, a1);
    b0 = fmaf(bflo(u3), w3, b0); b1 = fmaf(bfhi(u3), w3, b1);
  }
  for (; j < e1; ++j) {
    int s0 = colsrc[j];
    float w0 = dinv[s0] * di;
    uint32_t u0 = *(const uint32_t*)(xwb + (size_t)s0 * HID + c);
    a0 = fmaf(bflo(u0), w0, a0);
    a1 = fmaf(bfhi(u0), w0, a1);
  }
  a0 += b0;
  a1 += b1;
  a0 += bias[c];
  a1 += bias[c + 1];
  float s1 = a0 + a1, s2 = a0 * a0 + a1 * a1;
#pragma unroll
  for (int m = 32; m >= 1; m >>= 1) {
    s1 += __shfl_xor(s1, m);
    s2 += __shfl_xor(s2, m);
  }
  float mu = s1 * (1.0f / HID);
  float var = s2 * (1.0f / HID) - mu * mu;
  float rstd = rsqrtf(var + 1e-5f);
  float y0 = fmaxf((a0 - mu) * rstd * gamma[c] + beta[c], 0.0f);
  float y1 = fmaxf((a1 - mu) * rstd * gamma[c + 1] + beta[c + 1], 0.0f);
  if (L2) {
    uint32_t rh = *(const uint32_t*)(resh + (size_t)i * HID + c);
    uint32_t rl = *(const uint32_t*)(resl + (size_t)i * HID + c);
    y0 += bflo(rh) + bflo(rl);
    y1 += bfhi(rh) + bfhi(rl);
  }
  unsigned short ph0 = f2bf_rn(y0), ph1 = f2bf_rn(y1);
  uint32_t hw = (uint32_t)ph0 | ((uint32_t)ph1 << 16);
  uint32_t lw = (uint32_t)f2bf_rn(y0 - bf2f(ph0)) |
                ((uint32_t)f2bf_rn(y1 - bf2f(ph1)) << 16);
  *(uint32_t*)(oh + (size_t)i * HID + c) = hw;
  *(uint32_t*)(ol + (size_t)i * HID + c) = lw;
  if (L2) {
    float p[8];
#pragma unroll
    for (int h = 0; h < 8; ++h) p[h] = y0 * w[h][c] + y1 * w[h][c + 1];
#pragma unroll
    for (int m = 32; m >= 1; m >>= 1) {
#pragma unroll
      for (int h = 0; h < 8; ++h) p[h] += __shfl_xor(p[h], m);
    }
    if (lane == 0) {
      a_s[i * 4 + 0] = p[0]; a_s[i * 4 + 1] = p[1];
      a_s[i * 4 + 2] = p[2]; a_s[i * 4 + 3] = p[3];
      a_d[i * 4 + 0] = p[4]; a_d[i * 4 + 1] = p[5];
      a_d[i * 4 + 2] = p[6]; a_d[i * 4 + 3] = p[7];
    }
  }
}

// ---------------- fold Wgat into attention vectors (logits) ----------------
__global__ __launch_bounds__(256) void k_wprep(const float* __restrict__ Wgat,
                                               const float* __restrict__ att_src,
                                               const float* __restrict__ att_dst,
                                               float* __restrict__ waT) {
  int t = blockIdx.x * blockDim.x + threadIdx.x;  // 0..1023
  if (t >= 1024) return;
  int p = t >> 7, k = t & 127;
  int h = p & 3;
  const float* av = (p < 4 ? att_src : att_dst) + h * HID;
  const float* wrow = Wgat + (size_t)k * GATD + h * HID;
  float s = 0.f;
#pragma unroll 4
  for (int c = 0; c < HID; ++c) s = fmaf(wrow[c], av[c], s);
  waT[t] = s;
}

// ---------------- GAT softmax-aggregate on folded z table -> att planes [N,128] ----------------
// z row layout: elem c*4+h (head-interleaved). Output att = relu(sum_h agg_h + cb).
__global__ __launch_bounds__(256) void k_gat_agg2(const unsigned short* __restrict__ zb,
                                                  const float* __restrict__ a_s,
                                                  const float* __restrict__ a_d,
                                                  const int* __restrict__ rowp,
                                                  const int* __restrict__ colsrc,
                                                  const float* __restrict__ cb,
                                                  unsigned short* __restrict__ atth,
                                                  unsigned short* __restrict__ attl,
                                                  int n) {
  __shared__ float4 albuf[4][64];
  __shared__ int sbuf[4][64];
  const int lane = threadIdx.x & 63;
  const int wid = threadIdx.x >> 6;
  const int i = blockIdx.x * 4 + wid;
  if (i >= n) return;
  const float4 adv = *(const float4*)(a_d + i * 4);
  const float4 asv = *(const float4*)(a_s + i * 4);
  float es0 = lrelu02(asv.x + adv.x);
  float es1 = lrelu02(asv.y + adv.y);
  float es2 = lrelu02(asv.z + adv.z);
  float es3 = lrelu02(asv.w + adv.w);
  const int e0 = rowp[i], e1 = rowp[i + 1];
  // pass 1: max
  float m0 = es0, m1 = es1, m2 = es2, m3 = es3;
  for (int j = e0 + lane; j < e1; j += 64) {
    int s = colsrc[j];
    const float4 av = *(const float4*)(a_s + s * 4);
    m0 = fmaxf(m0, lrelu02(av.x + adv.x));
    m1 = fmaxf(m1, lrelu02(av.y + adv.y));
    m2 = fmaxf(m2, lrelu02(av.z + adv.z));
    m3 = fmaxf(m3, lrelu02(av.w + adv.w));
  }
#pragma unroll
  for (int m = 32; m >= 1; m >>= 1) {
    m0 = fmaxf(m0, __shfl_xor(m0, m));
    m1 = fmaxf(m1, __shfl_xor(m1, m));
    m2 = fmaxf(m2, __shfl_xor(m2, m));
    m3 = fmaxf(m3, __shfl_xor(m3, m));
  }
  // pass 2: denom
  float d0 = 0.f, d1 = 0.f, d2 = 0.f, d3 = 0.f;
  for (int j = e0 + lane; j < e1; j += 64) {
    int s = colsrc[j];
    const float4 av = *(const float4*)(a_s + s * 4);
    d0 += __expf(lrelu02(av.x + adv.x) - m0);
    d1 += __expf(lrelu02(av.y + adv.y) - m1);
    d2 += __expf(lrelu02(av.z + adv.z) - m2);
    d3 += __expf(lrelu02(av.w + adv.w) - m3);
  }
#pragma unroll
  for (int m = 32; m >= 1; m >>= 1) {
    d0 += __shfl_xor(d0, m);
    d1 += __shfl_xor(d1, m);
    d2 += __shfl_xor(d2, m);
    d3 += __shfl_xor(d3, m);
  }
  d0 += __expf(es0 - m0);
  d1 += __expf(es1 - m1);
  d2 += __expf(es2 - m2);
  d3 += __expf(es3 - m3);
  const float inv0 = 1.0f / d0, inv1 = 1.0f / d1, inv2 = 1.0f / d2, inv3 = 1.0f / d3;
  // self term (alpha for all 4 heads)
  const float4 asf = make_float4(__expf(es0 - m0) * inv0, __expf(es1 - m1) * inv1,
                                 __expf(es2 - m2) * inv2, __expf(es3 - m3) * inv3);
  const int col8 = lane * 8;  // elems [lane*8, lane*8+8): c0=lane*2 (h0..3), c1 (h0..3)
  uint4 u = *(const uint4*)(zb + (size_t)i * GATD + col8);
  float4 accC0 = make_float4(bflo(u.x) * asf.x, bfhi(u.x) * asf.y,
                             bflo(u.y) * asf.z, bfhi(u.y) * asf.w);
  float4 accC1 = make_float4(bflo(u.z) * asf.x, bfhi(u.z) * asf.y,
                             bflo(u.w) * asf.z, bfhi(u.w) * asf.w);
  // pass 3: chunked -- 64 lanes compute 64 edge-alphas, then all lanes stream messages
  for (int b = e0; b < e1; b += 64) {
    int j = b + lane;
    if (j < e1) {
      int s = colsrc[j];
      const float4 av = *(const float4*)(a_s + s * 4);
      albuf[wid][lane] = make_float4(__expf(lrelu02(av.x + adv.x) - m0) * inv0,
                                     __expf(lrelu02(av.y + adv.y) - m1) * inv1,
                                     __expf(lrelu02(av.z + adv.z) - m2) * inv2,
                                     __expf(lrelu02(av.w + adv.w) - m3) * inv3);
      sbuf[wid][lane] = s;
    }
    asm volatile("s_waitcnt lgkmcnt(0)" ::: "memory");
    const int cnt = min(64, e1 - b);
    for (int t = 0; t < cnt; ++t) {
      float4 a4 = albuf[wid][t];
      int s = sbuf[wid][t];
      uint4 w = *(const uint4*)(zb + (size_t)s * GATD + col8);
      accC0.x = fmaf(bflo(w.x), a4.x, accC0.x);
      accC0.y = fmaf(bfhi(w.x), a4.y, accC0.y);
      accC0.z = fmaf(bflo(w.y), a4.z, accC0.z);
      accC0.w = fmaf(bfhi(w.y), a4.w, accC0.w);
      accC1.x = fmaf(bflo(w.z), a4.x, accC1.x);
      accC1.y = fmaf(bfhi(w.z), a4.y, accC1.y);
      accC1.z = fmaf(bflo(w.w), a4.z, accC1.z);
      accC1.w = fmaf(bfhi(w.w), a4.w, accC1.w);
    }
  }
  const int c0 = lane * 2;
  float2 cbv = *(const float2*)(cb + c0);
  float o0 = fmaxf(accC0.x + accC0.y + accC0.z + accC0.w + cbv.x, 0.0f);
  float o1 = fmaxf(accC1.x + accC1.y + accC1.z + accC1.w + cbv.y, 0.0f);
  unsigned short ph0 = f2bf_rn(o0), ph1 = f2bf_rn(o1);
  uint32_t hw = (uint32_t)ph0 | ((uint32_t)ph1 << 16);
  uint32_t lw = (uint32_t)f2bf_rn(o0 - bf2f(ph0)) |
                ((uint32_t)f2bf_rn(o1 - bf2f(ph1)) << 16);
  *(uint32_t*)(atth + (size_t)i * HID + c0) = hw;
  *(uint32_t*)(attl + (size_t)i * HID + c0) = lw;
}

extern "C" void kernel_launch(void* const* d_in, const int* in_sizes, int n_in,
                              void* d_out, int out_size, void* d_ws, size_t ws_size,
                              hipStream_t stream) {
  const float* x = (const float*)d_in[0];
  const int* ei = (const int*)d_in[1];
  const float* Win = (const float*)d_in[2];
  const float* bin = (const float*)d_in[3];
  const float* Wg1 = (const float*)d_in[4];
  const float* bg1 = (const float*)d_in[5];
  const float* g1g = (const float*)d_in[6];
  const float* g1b = (const float*)d_in[7];
  const float* Wg2 = (const float*)d_in[8];
  const float* bg2 = (const float*)d_in[9];
  const float* g2g = (const float*)d_in[10];
  const float* g2b = (const float*)d_in[11];
  const float* Wgat = (const float*)d_in[12];
  const float* att_s = (const float*)d_in[13];
  const float* att_d = (const float*)d_in[14];
  const float* bgat = (const float*)d_in[15];
  const float* Wao = (const float*)d_in[16];
  const float* bao = (const float*)d_in[17];
  const float* Wout = (const float*)d_in[18];
  const float* bout = (const float*)d_in[19];

  const int N = in_sizes[0] / 256;
  const int E = in_sizes[1] / 2;
  const int* src = ei;
  const int* dst = ei + E;

  // ---- workspace layout (bytes), ~145 MB ----
  char* base = (char*)d_ws;
  size_t off = 0;
  unsigned short* h0h = (unsigned short*)(base + off); off += (size_t)N * HID * 2;
  unsigned short* h0l = (unsigned short*)(base + off); off += (size_t)N * HID * 2;
  unsigned short* x1h = (unsigned short*)(base + off); off += (size_t)N * HID * 2;
  unsigned short* x1l = (unsigned short*)(base + off); off += (size_t)N * HID * 2;
  unsigned short* xwb = (unsigned short*)(base + off); off += (size_t)N * HID * 2;
  unsigned short* x2h = (unsigned short*)(base + off); off += (size_t)N * HID * 2;
  unsigned short* x2l = (unsigned short*)(base + off); off += (size_t)N * HID * 2;
  unsigned short* atth = x2h;  // x2 planes dead after z GEMM
  unsigned short* attl = x2l;
  unsigned short* zb = (unsigned short*)(base + off); off += (size_t)N * GATD * 2;
  float* dinv = (float*)(base + off);                 off += (size_t)N * 4;
  float* a_s = (float*)(base + off);                  off += (size_t)N * 16;
  float* a_d = (float*)(base + off);                  off += (size_t)N * 16;
  float* waT = (float*)(base + off);                  off += 4096;
  float* cb = (float*)(base + off);                   off += 512;
  unsigned short *WinTh, *WinTl, *Wg1Th, *Wg1Tl, *Wg2Th, *Wg2Tl, *WoutTh, *WoutTl;
  unsigned short *VTh, *VTl;
  WinTh = (unsigned short*)(base + off);  off += 256 * 128 * 2;
  WinTl = (unsigned short*)(base + off);  off += 256 * 128 * 2;
  Wg1Th = (unsigned short*)(base + off);  off += 128 * 128 * 2;
  Wg1Tl = (unsigned short*)(base + off);  off += 128 * 128 * 2;
  Wg2Th = (unsigned short*)(base + off);  off += 128 * 128 * 2;
  Wg2Tl = (unsigned short*)(base + off);  off += 128 * 128 * 2;
  VTh = (unsigned short*)(base + off);    off += 512 * 128 * 2;
  VTl = (unsigned short*)(base + off);    off += 512 * 128 * 2;
  WoutTh = (unsigned short*)(base + off); off += 128 * 64 * 2;
  WoutTl = (unsigned short*)(base + off); off += 128 * 64 * 2;
  int* rowp = (int*)(base + off);   off += (size_t)(N + 1) * 4;
  int* colsrc = (int*)(base + off); off += (size_t)E * 4;
  const int nb2 = (N + 1023) / 1024;
  int* bsum = (int*)(base + off);   off += (size_t)(nb2 + 2) * 4;
  int* cnt = (int*)zb;  // alias: dead before zb is written
  int* cur = cnt + N;

  const int eb = (E + TPB - 1) / TPB;
  const int zbk = (2 * N + TPB - 1) / TPB;
  const int ab = (N + 3) / 4;
  const int gm = (N + 63) / 64;

  // CSR + prep
  k_zero<<<zbk, TPB, 0, stream>>>(cnt, 2 * N);
  k_hist<<<eb, TPB, 0, stream>>>(dst, cnt, E);
  k_scan_blk<<<nb2, 256, 0, stream>>>(cnt, rowp, bsum, dinv, N);
  k_scan_top<<<1, 256, 0, stream>>>(bsum, nb2);
  k_scan_add<<<(N + 255) / 256, 256, 0, stream>>>(rowp, bsum, N, nb2);
  k_fill<<<eb, TPB, 0, stream>>>(src, dst, rowp, cur, colsrc, E);
  k_wprep<<<4, 256, 0, stream>>>(Wgat, att_s, att_d, waT);
  k_vprep<<<256, 256, 0, stream>>>(Wgat, Wao, VTh, VTl);
  k_cbias<<<1, 128, 0, stream>>>(bgat, Wao, bao, cb);
  k_splitw_all<<<(73728 + 255) / 256, 256, 0, stream>>>(
      Win, Wg1, Wg2, Wout, WinTh, WinTl, Wg1Th, Wg1Tl, Wg2Th, Wg2Tl, WoutTh, WoutTl);

  // h0 = relu(x @ Win + bin) -> planes    [fp32 A split in regs]
  k_gemm5<256, 64, 128, true, true, 2, 1><<<dim3(gm, 1), 256, 0, stream>>>(
      (const unsigned short*)x, nullptr, WinTh, WinTl, bin, h0h, h0l, N, 128);
  // GCN layer 1: xwb = bf16(h0 @ Wg1)
  k_gemm5<128, 64, 128, false, false, 1, 0><<<dim3(gm, 1), 256, 0, stream>>>(
      h0h, h0l, Wg1Th, Wg1Tl, nullptr, xwb, nullptr, N, 128);
  k_gcn_agg<false><<<ab, 256, 0, stream>>>(xwb, dinv, rowp, colsrc, bg1, g1g, g1b,
                                           nullptr, nullptr, x1h, x1l,
                                           nullptr, nullptr, nullptr, N);
  // GCN layer 2 (+residual, +fused GAT logits)
  k_gemm5<128, 64, 128, false, false, 1, 0><<<dim3(gm, 1), 256, 0, stream>>>(
      x1h, x1l, Wg2Th, Wg2Tl, nullptr, xwb, nullptr, N, 128);
  k_gcn_agg<true><<<ab, 256, 0, stream>>>(xwb, dinv, rowp, colsrc, bg2, g2g, g2b,
                                          x1h, x1l, x2h, x2l, waT, a_s, a_d, N);
  // z = bf16(x2 @ V)  [head-interleaved cols; NCB=256, KC=32, y=2]
  k_gemm5<128, 32, 256, false, false, 1, 0><<<dim3(gm, 2), 256, 0, stream>>>(
      x2h, x2l, VTh, VTl, nullptr, zb, nullptr, N, 512);
  // softmax-aggregate on z -> att planes directly (Wao folded; GEMM eliminated)
  k_gat_agg2<<<ab, 256, 0, stream>>>(zb, a_s, a_d, rowp, colsrc, cb, atth, attl, N);
  // out = att @ Wout + bout (fp32)
  k_gemm5<128, 128, 64, false, true, 0, 0><<<dim3(gm, 1), 256, 0, stream>>>(
      atth, attl, WoutTh, WoutTl, bout, d_out, nullptr, N, 64);
}